// Round 8
// baseline (585.224 us; speedup 1.0000x reference)
//
#include <hip/hip_runtime.h>
#include <math.h>

#define BB 64
#define T_FR 200
#define NA 48000
#define NBINS 24001

typedef __attribute__((ext_vector_type(4))) float f32x4;
typedef __attribute__((ext_vector_type(8))) short bf16x8;

__device__ __forceinline__ unsigned short f2bf(float x)
{
    unsigned u = __float_as_uint(x);
    u = (u + 0x7FFFu + ((u >> 16) & 1u)) >> 16;
    return (unsigned short)u;
}
__device__ __forceinline__ float bf2f(unsigned short h)
{
    return __uint_as_float(((unsigned)h) << 16);
}

__device__ inline float2 cmul(float2 a, float2 b)
{
    return make_float2(a.x * b.x - a.y * b.y, a.x * b.y + a.y * b.x);
}

// e^{2*pi*i*rev} via HW transcendentals (args in revolutions)
__device__ __forceinline__ float2 cis_rev(float rev)
{
    return make_float2(__builtin_amdgcn_cosf(rev), __builtin_amdgcn_sinf(rev));
}

// ---------------- root tables ----------------
template<int R> __device__ __forceinline__ void fill_roots(float (&cr)[R], float (&si)[R]);
template<> __device__ __forceinline__ void fill_roots<3>(float (&cr)[3], float (&si)[3])
{
    const float S = 0.86602540378443865f;
    cr[0]=1.f; cr[1]=-0.5f; cr[2]=-0.5f;
    si[0]=0.f; si[1]=S;     si[2]=-S;
}
template<> __device__ __forceinline__ void fill_roots<4>(float (&cr)[4], float (&si)[4])
{
    cr[0]=1.f; cr[1]=0.f; cr[2]=-1.f; cr[3]=0.f;
    si[0]=0.f; si[1]=1.f; si[2]=0.f;  si[3]=-1.f;
}
template<> __device__ __forceinline__ void fill_roots<5>(float (&cr)[5], float (&si)[5])
{
    cr[0]=1.f; cr[1]=0.30901699437494742f; cr[2]=-0.80901699437494742f;
    cr[3]=-0.80901699437494742f; cr[4]=0.30901699437494742f;
    si[0]=0.f; si[1]=0.95105651629515357f; si[2]=0.58778525229247313f;
    si[3]=-0.58778525229247313f; si[4]=-0.95105651629515357f;
}
template<> __device__ __forceinline__ void fill_roots<8>(float (&cr)[8], float (&si)[8])
{
    const float C = 0.70710678118654752f;
    cr[0]=1.f; cr[1]=C;  cr[2]=0.f;  cr[3]=-C; cr[4]=-1.f; cr[5]=-C;  cr[6]=0.f;  cr[7]=C;
    si[0]=0.f; si[1]=C;  si[2]=1.f;  si[3]=C;  si[4]=0.f;  si[5]=-C;  si[6]=-1.f; si[7]=-C;
}

template<int S, int R>
__device__ __forceinline__ void dftR(float2 (&v)[R])
{
    float cr[R], si[R];
    fill_roots<R>(cr, si);
    float2 o[R];
#pragma unroll
    for (int k = 0; k < R; ++k) {
        float re = 0.f, im = 0.f;
#pragma unroll
        for (int j = 0; j < R; ++j) {
            int m = (j * k) % R;
            float ur = cr[m], ui = (S > 0) ? si[m] : -si[m];
            re += v[j].x * ur - v[j].y * ui;
            im += v[j].x * ui + v[j].y * ur;
        }
        o[k] = make_float2(re, im);
    }
#pragma unroll
    for (int k = 0; k < R; ++k) v[k] = o[k];
}

__device__ __constant__ float C25R[17] = {1.f,0.968583161f,0.876306680f,0.728968627f,0.535826795f,0.309016994f,0.062790520f,-0.187381315f,-0.425779292f,-0.637423990f,-0.809016994f,-0.929776486f,-0.992114701f,-0.992114701f,-0.929776486f,-0.809016994f,-0.637423990f};
__device__ __constant__ float C25I[17] = {0.f,0.248689887f,0.481753674f,0.684547106f,0.844327926f,0.951056516f,0.998026728f,0.982287251f,0.904827052f,0.770513243f,0.587785252f,0.368124553f,0.125333234f,-0.125333234f,-0.368124553f,-0.587785252f,-0.770513243f};
__device__ __constant__ float C15R[9] = {1.f,0.913545458f,0.669130606f,0.309016994f,-0.104528463f,-0.5f,-0.809016994f,-0.978147601f,-0.978147601f};
__device__ __constant__ float C15I[9] = {0.f,0.406736643f,0.743144825f,0.951056516f,0.994521895f,0.866025404f,0.587785252f,0.207911691f,-0.207911691f};
__device__ __constant__ float C16R[10] = {1.f,0.923879533f,0.707106781f,0.382683432f,0.f,-0.382683432f,-0.707106781f,-0.923879533f,-1.f,-0.923879533f};
__device__ __constant__ float C16I[10] = {0.f,0.382683432f,0.707106781f,0.923879533f,1.f,0.923879533f,0.707106781f,0.382683432f,0.f,-0.382683432f};

template<int S> __device__ __forceinline__ float2 tw25(int m){ return make_float2(C25R[m], S>0? C25I[m] : -C25I[m]); }
template<int S> __device__ __forceinline__ float2 tw15(int m){ return make_float2(C15R[m], S>0? C15I[m] : -C15I[m]); }
template<int S> __device__ __forceinline__ float2 tw16(int m){ return make_float2(C16R[m], S>0? C16I[m] : -C16I[m]); }

// ======== in-place micro-stages. Each item's read-set == write-set. ========
// --- 200 = 8 x (5 x 5), row slots: natural time at slot n ---
template<int SGN> __device__ __forceinline__ void s200_1(float2* row, int g)
{
    float2 v[8];
#pragma unroll
    for (int j = 0; j < 8; ++j) v[j] = row[25 * j + g];
    float gs = (float)(SGN * g) * (1.f / 200.f);
    if (SGN < 0) {
        dftR<-1, 8>(v);
#pragma unroll
        for (int k = 1; k < 8; ++k) v[k] = cmul(v[k], cis_rev(gs * (float)k));
    } else {
#pragma unroll
        for (int k = 1; k < 8; ++k) v[k] = cmul(v[k], cis_rev(gs * (float)k));
        dftR<+1, 8>(v);
    }
#pragma unroll
    for (int j = 0; j < 8; ++j) row[25 * j + g] = v[j];
}
template<int SGN> __device__ __forceinline__ void s200_2a(float2* row, int k1, int bq)
{
    float2 u[5];
    int base = 25 * k1 + bq;
#pragma unroll
    for (int a = 0; a < 5; ++a) u[a] = row[base + 5 * a];
    if (SGN < 0) {
        dftR<-1, 5>(u);
#pragma unroll
        for (int c = 1; c < 5; ++c) if (bq) u[c] = cmul(u[c], tw25<-1>(c * bq));
    } else {
#pragma unroll
        for (int c = 1; c < 5; ++c) if (bq) u[c] = cmul(u[c], tw25<+1>(c * bq));
        dftR<+1, 5>(u);
    }
#pragma unroll
    for (int c = 0; c < 5; ++c) row[base + 5 * c] = u[c];
}

// --- 240 = (4x4) x (5x3), column slots stride 1 ---
template<int SGN> __device__ __forceinline__ void s240_1a(float2* col, int g, int bq)
{
    float2 u[4];
#pragma unroll
    for (int a = 0; a < 4; ++a) u[a] = col[15 * (4 * a + bq) + g];
    if (SGN < 0) {
        dftR<-1, 4>(u);
#pragma unroll
        for (int c = 1; c < 4; ++c) if (bq) u[c] = cmul(u[c], tw16<-1>(c * bq));
    } else {
#pragma unroll
        for (int c = 1; c < 4; ++c) if (bq) u[c] = cmul(u[c], tw16<+1>(c * bq));
        dftR<+1, 4>(u);
    }
#pragma unroll
    for (int c = 0; c < 4; ++c) col[15 * (4 * c + bq) + g] = u[c];
}
template<int SGN> __device__ __forceinline__ void s240_1b(float2* col, int g, int c)
{
    float2 u[4];
    float gs = (float)(SGN * g) * (1.f / 240.f);
#pragma unroll
    for (int i = 0; i < 4; ++i) u[i] = col[15 * (4 * c + i) + g];
    if (SGN < 0) {
        dftR<-1, 4>(u);
#pragma unroll
        for (int d = 0; d < 4; ++d) { int k1 = c + 4 * d; if (k1) u[d] = cmul(u[d], cis_rev(gs * (float)k1)); }
    } else {
#pragma unroll
        for (int d = 0; d < 4; ++d) { int k1 = c + 4 * d; if (k1) u[d] = cmul(u[d], cis_rev(gs * (float)k1)); }
        dftR<+1, 4>(u);
    }
#pragma unroll
    for (int i = 0; i < 4; ++i) col[15 * (4 * c + i) + g] = u[i];
}
template<int SGN> __device__ __forceinline__ void s240_2a(float2* col, int p, int bq)
{
    float2 u[5];
    int base = 15 * p + bq;
#pragma unroll
    for (int a = 0; a < 5; ++a) u[a] = col[base + 3 * a];
    if (SGN < 0) {
        dftR<-1, 5>(u);
#pragma unroll
        for (int c = 1; c < 5; ++c) if (bq) u[c] = cmul(u[c], tw15<-1>(c * bq));
    } else {
#pragma unroll
        for (int c = 1; c < 5; ++c) if (bq) u[c] = cmul(u[c], tw15<+1>(c * bq));
        dftR<+1, 5>(u);
    }
#pragma unroll
    for (int c = 0; c < 5; ++c) col[base + 3 * c] = u[c];
}
__device__ __forceinline__ int p2k1(int p) { return ((p & 3) << 2) | (p >> 2); }

// ================= MFMA conv (unchanged, verified) =================
template<int NT, int TAPS, int CHUNKS, int CINP, int COUTP>
__global__ __launch_bounds__(256) void conv_mfma_kernel(
    const unsigned short* __restrict__ xT, int tRowsIn,
    const unsigned short* __restrict__ wT,
    const float* __restrict__ bias,
    unsigned short* __restrict__ outT, int tRowsOut, int tOffOut)
{
    const int b = blockIdx.y;
    const int t0 = blockIdx.x * 16;
    const int tid = threadIdx.x;
    const int wave = tid >> 6;
    const int lane = tid & 63;
    const int m = lane & 15;
    const int quad = lane >> 4;
    const int n0 = wave * (NT * 16);

    f32x4 acc[NT];
#pragma unroll
    for (int nt = 0; nt < NT; ++nt) acc[nt] = (f32x4){0.f, 0.f, 0.f, 0.f};

    const unsigned short* xb = xT + (size_t)b * tRowsIn * CINP;
#pragma unroll
    for (int kw = 0; kw < TAPS; ++kw) {
        const unsigned short* wk = wT + (size_t)kw * COUTP * CINP;
        const unsigned short* xrow = xb + (size_t)(t0 + kw + m) * CINP + quad * 8;
#pragma unroll
        for (int ch = 0; ch < CHUNKS; ++ch) {
            const int k0 = ch * 32;
            bf16x8 a = *(const bf16x8*)(xrow + k0);
#pragma unroll
            for (int nt = 0; nt < NT; ++nt) {
                bf16x8 bfr = *(const bf16x8*)(wk + (size_t)(n0 + nt * 16 + m) * CINP + k0 + quad * 8);
                acc[nt] = __builtin_amdgcn_mfma_f32_16x16x32_bf16(a, bfr, acc[nt], 0, 0, 0);
            }
        }
    }
#pragma unroll
    for (int nt = 0; nt < NT; ++nt) {
        const int n = n0 + nt * 16 + m;
        const float bz = bias[n];
#pragma unroll
        for (int r = 0; r < 4; ++r) {
            const int t = t0 + quad * 4 + r;
            if (t < 200) {
                float v = acc[nt][r] + bz;
                v = (v >= 0.f) ? v : 0.1f * v;
                outT[((size_t)b * tRowsOut + t + tOffOut) * COUTP + n] = f2bf(v);
            }
        }
    }
}

__global__ void prep_x1_kernel(const float* __restrict__ cond, const float* __restrict__ f0,
                               unsigned short* __restrict__ xpT1)
{
    int idx = blockIdx.x * 256 + threadIdx.x;
    const int total = BB * 212 * 160;
    if (idx >= total) return;
    int i = idx % 160;
    int rest = idx / 160;
    int tp = rest % 212;
    int b = rest / 212;
    int tt = tp - 2;
    float v = 0.f;
    if (tt >= 0 && tt < 200) {
        if (i < 128) v = cond[((size_t)b * 128 + i) * 200 + tt];
        else if (i == 128) v = (f0[b * 200 + tt] > 0.f) ? 1.f : 0.f;
    }
    xpT1[idx] = f2bf(v);
}

template<int TAPS, int CINR, int CINP, int COUTP>
__global__ void prep_w_kernel(const float* __restrict__ w, unsigned short* __restrict__ wT)
{
    int idx = blockIdx.x * 256 + threadIdx.x;
    const int total = TAPS * COUTP * CINP;
    if (idx >= total) return;
    int i = idx % CINP;
    int rest = idx / CINP;
    int o = rest % COUTP;
    int kw = rest / COUTP;
    float v = (i < CINR) ? w[((size_t)o * CINR + i) * TAPS + kw] : 0.f;
    wT[idx] = f2bf(v);
}

__global__ void zero16_kernel(uint4* __restrict__ p, int n16)
{
    int idx = blockIdx.x * 256 + threadIdx.x;
    if (idx < n16) p[idx] = make_uint4(0, 0, 0, 0);
}

// ================= FFT passes =================

// pass A: wn -> I[b][kg][n2] (8 columns/block, 25x64 grid)
__global__ __launch_bounds__(256) void passA_kernel(const float* __restrict__ wn,
                                                    float2* __restrict__ I)
{
    __shared__ float2 L[8 * 241];
    int b = blockIdx.y;
    int n20 = blockIdx.x * 8;
    int tid = threadIdx.x;
    for (int idx = tid; idx < 1920; idx += 256) {
        int n1 = idx >> 3, j = idx & 7;
        L[j * 241 + n1] = make_float2(wn[(size_t)b * NA + n1 * 200 + n20 + j], 0.f);
    }
    __syncthreads();
    for (int idx = tid; idx < 480; idx += 256) {
        int j = idx & 7, r = idx >> 3;
        s240_1a<-1>(L + j * 241, r >> 2, r & 3);
    }
    __syncthreads();
    for (int idx = tid; idx < 480; idx += 256) {
        int j = idx & 7, r = idx >> 3;
        s240_1b<-1>(L + j * 241, r >> 2, r & 3);
    }
    __syncthreads();
    for (int idx = tid; idx < 384; idx += 256) {
        int j = idx & 7, r = idx >> 3;
        s240_2a<-1>(L + j * 241, r / 3, r - 3 * (r / 3));
    }
    __syncthreads();
    for (int idx = tid; idx < 640; idx += 256) {
        int j = idx & 7, r = idx >> 3;
        int p = r / 5, c = r - 5 * p;
        float2* col = L + j * 241;
        float2 u[3];
#pragma unroll
        for (int i = 0; i < 3; ++i) u[i] = col[15 * p + 3 * c + i];
        dftR<-1, 3>(u);
        int k1 = p2k1(p);
        int n2 = n20 + j;
#pragma unroll
        for (int d = 0; d < 3; ++d) {
            int kg = k1 + 16 * (c + 5 * d);
            float2 tw = cis_rev(-(float)(n2 * kg) * (1.f / (float)NA));
            I[(size_t)b * NA + kg * 200 + n2] = cmul(u[d], tw);
        }
    }
}

// pass B: 10 rows/block (24x64 grid); fwd -> mul(+Parseval) -> inv, all in one LDS buffer
template<int MODE>
__global__ __launch_bounds__(256) void passB_kernel(float2* __restrict__ I,
    const float* __restrict__ avg_shape, const float* __restrict__ fbins,
    const float* __restrict__ loc_w, float* __restrict__ acc, float* __restrict__ z0)
{
    __shared__ float2 L[10 * 202];
    __shared__ float gsh[32];
    int b = blockIdx.y;
    int row0 = blockIdx.x * 10;
    int tid = threadIdx.x;
    if (MODE == 0) { if (tid < 32) gsh[tid] = avg_shape[b * 32 + tid]; }
    else           { if (tid < 5)  gsh[tid] = loc_w[b * 5 + tid]; }
    for (int idx = tid; idx < 2000; idx += 256) {
        int row = idx / 200, e = idx - row * 200;
        L[row * 202 + e] = I[(size_t)b * NA + (row0 + row) * 200 + e];
    }
    __syncthreads();
    for (int idx = tid; idx < 250; idx += 256) {
        int row = idx / 25, g = idx - row * 25;
        s200_1<-1>(L + row * 202, g);
    }
    __syncthreads();
    for (int idx = tid; idx < 400; idx += 256) {
        int row = idx / 40, r = idx - row * 40;
        s200_2a<-1>(L + row * 202, r / 5, r - 5 * (r / 5));
    }
    __syncthreads();
    float part = 0.f;
    for (int idx = tid; idx < 400; idx += 256) {
        int row = idx / 40, r = idx - row * 40;
        int k1r = r / 5, c = r - 5 * k1r;
        float2* rw = L + row * 202;
        int base = 25 * k1r + 5 * c;
        float2 u[5];
#pragma unroll
        for (int i = 0; i < 5; ++i) u[i] = rw[base + i];
        dftR<-1, 5>(u);
        int k1g = row0 + row;
#pragma unroll
        for (int d = 0; d < 5; ++d) {
            int k2 = k1r + 8 * (c + 5 * d);
            int k = k1g + 240 * k2;
            int kbin = min(k, NA - k);
            float2 X = u[d];
            if (MODE == 0) {
                int jj = (kbin * 32) / NBINS;
                if (jj < 31 && (NBINS * (jj + 1)) / 32 <= kbin) ++jj;
                float g2 = gsh[jj];
                float2 Z = make_float2(X.x * g2, X.y * g2);
                part += Z.x * Z.x + Z.y * Z.y;
                if (k == 0) z0[b] = Z.x;
                u[d] = make_float2(Z.x * (1.f / NA), Z.y * (1.f / NA));
            } else {
                float tf = 0.f;
#pragma unroll
                for (int cc = 0; cc < 5; ++cc) tf += gsh[cc] * fbins[cc * NBINS + kbin];
                tf *= (1.f / NA);
                u[d] = make_float2(X.x * tf, X.y * tf);
            }
        }
#pragma unroll
        for (int d = 0; d < 5; ++d) rw[base + d] = u[d];
    }
    if (MODE == 0) {
        for (int o = 32; o > 0; o >>= 1) part += __shfl_down(part, o);
        if ((tid & 63) == 0) atomicAdd(&acc[b], part);
    }
    __syncthreads();
    // inverse: 5-DFT over d -> b
    for (int idx = tid; idx < 400; idx += 256) {
        int row = idx / 40, r = idx - row * 40;
        int k1r = r / 5, c = r - 5 * k1r;
        float2* rw = L + row * 202;
        int base = 25 * k1r + 5 * c;
        float2 u[5];
#pragma unroll
        for (int i = 0; i < 5; ++i) u[i] = rw[base + i];
        dftR<+1, 5>(u);
#pragma unroll
        for (int i = 0; i < 5; ++i) rw[base + i] = u[i];
    }
    __syncthreads();
    for (int idx = tid; idx < 400; idx += 256) {
        int row = idx / 40, r = idx - row * 40;
        s200_2a<+1>(L + row * 202, r / 5, r - 5 * (r / 5));
    }
    __syncthreads();
    for (int idx = tid; idx < 250; idx += 256) {
        int row = idx / 25, g = idx - row * 25;
        s200_1<+1>(L + row * 202, g);
    }
    __syncthreads();
    for (int idx = tid; idx < 2000; idx += 256) {
        int row = idx / 200, n2 = idx - row * 200;
        int k1g = row0 + row;
        float2 tw = cis_rev((float)(n2 * k1g) * (1.f / (float)NA));
        I[(size_t)b * NA + k1g * 200 + n2] = cmul(L[row * 202 + n2], tw);
    }
}

// pass C: inv240 -> mod -> fwd240 (8 columns/block, 25x64 grid)
__global__ __launch_bounds__(256) void passC_kernel(float2* __restrict__ I,
    const float* __restrict__ control, const float* __restrict__ f0,
    const float* __restrict__ scale)
{
    __shared__ float2 L[8 * 241];
    __shared__ float ctl3[600];
    __shared__ float f0s[200];
    int b = blockIdx.y;
    int n20 = blockIdx.x * 8;
    int tid = threadIdx.x;
    for (int i = tid; i < 600; i += 256) ctl3[i] = control[(size_t)b * 1600 + i];
    for (int i = tid; i < 200; i += 256) f0s[i] = f0[b * 200 + i];
    // I2b: direct global read -> 3-DFT -> LDS
    for (int idx = tid; idx < 640; idx += 256) {
        int j = idx & 7, r = idx >> 3;
        int p = r / 5, c = r - 5 * p;
        int k1 = p2k1(p);
        int n2 = n20 + j;
        float2 u[3];
#pragma unroll
        for (int d = 0; d < 3; ++d) {
            int kg = k1 + 16 * (c + 5 * d);
            u[d] = I[(size_t)b * NA + kg * 200 + n2];
        }
        dftR<+1, 3>(u);
        float2* col = L + j * 241;
#pragma unroll
        for (int i = 0; i < 3; ++i) col[15 * p + 3 * c + i] = u[i];
    }
    __syncthreads();
    for (int idx = tid; idx < 384; idx += 256) {
        int j = idx & 7, r = idx >> 3;
        s240_2a<+1>(L + j * 241, r / 3, r - 3 * (r / 3));
    }
    __syncthreads();
    for (int idx = tid; idx < 480; idx += 256) {
        int j = idx & 7, r = idx >> 3;
        s240_1b<+1>(L + j * 241, r >> 2, r & 3);
    }
    __syncthreads();
    for (int idx = tid; idx < 480; idx += 256) {
        int j = idx & 7, r = idx >> 3;
        s240_1a<+1>(L + j * 241, r >> 2, r & 3);
    }
    __syncthreads();
    // mod (natural time at slots)
    float sc = scale[b];
    for (int idx = tid; idx < 1920; idx += 256) {
        int n1 = idx >> 3, j = idx & 7;
        int n2 = n20 + j;
        int n = 200 * n1 + n2;
        float sf = ((float)n + 0.5f) * (1.f / 240.f) - 0.5f;
        sf = fminf(fmaxf(sf, 0.f), 199.f);
        int i0 = (int)sf;
        int i1 = min(i0 + 1, 199);
        float w = sf - (float)i0;
        float inh = ctl3[i0] * (1.f - w) + ctl3[i1] * w;
        float exh = ctl3[200 + i0] * (1.f - w) + ctl3[200 + i1] * w;
        float pr  = ctl3[400 + i0] * (1.f - w) + ctl3[400 + i1] * w;
        float v0 = f0s[i0] > 0.f ? 1.f : 0.f;
        float v1 = f0s[i1] > 0.f ? 1.f : 0.f;
        float vv = v0 * (1.f - w) + v1 * w;
        float m = inh * (1.f - vv) + exh * pr;
        float y = L[j * 241 + n1].x * sc;
        L[j * 241 + n1] = make_float2(y * m, 0.f);
    }
    __syncthreads();
    for (int idx = tid; idx < 480; idx += 256) {
        int j = idx & 7, r = idx >> 3;
        s240_1a<-1>(L + j * 241, r >> 2, r & 3);
    }
    __syncthreads();
    for (int idx = tid; idx < 480; idx += 256) {
        int j = idx & 7, r = idx >> 3;
        s240_1b<-1>(L + j * 241, r >> 2, r & 3);
    }
    __syncthreads();
    for (int idx = tid; idx < 384; idx += 256) {
        int j = idx & 7, r = idx >> 3;
        s240_2a<-1>(L + j * 241, r / 3, r - 3 * (r / 3));
    }
    __syncthreads();
    for (int idx = tid; idx < 640; idx += 256) {
        int j = idx & 7, r = idx >> 3;
        int p = r / 5, c = r - 5 * p;
        float2* col = L + j * 241;
        float2 u[3];
#pragma unroll
        for (int i = 0; i < 3; ++i) u[i] = col[15 * p + 3 * c + i];
        dftR<-1, 3>(u);
        int k1 = p2k1(p);
        int n2 = n20 + j;
#pragma unroll
        for (int d = 0; d < 3; ++d) {
            int kg = k1 + 16 * (c + 5 * d);
            float2 tw = cis_rev(-(float)(n2 * kg) * (1.f / (float)NA));
            I[(size_t)b * NA + kg * 200 + n2] = cmul(u[d], tw);
        }
    }
}

// pass D: inv240 -> real out
__global__ __launch_bounds__(256) void passD_kernel(const float2* __restrict__ I,
                                                    float* __restrict__ out)
{
    __shared__ float2 L[8 * 241];
    int b = blockIdx.y;
    int n20 = blockIdx.x * 8;
    int tid = threadIdx.x;
    for (int idx = tid; idx < 640; idx += 256) {
        int j = idx & 7, r = idx >> 3;
        int p = r / 5, c = r - 5 * p;
        int k1 = p2k1(p);
        int n2 = n20 + j;
        float2 u[3];
#pragma unroll
        for (int d = 0; d < 3; ++d) {
            int kg = k1 + 16 * (c + 5 * d);
            u[d] = I[(size_t)b * NA + kg * 200 + n2];
        }
        dftR<+1, 3>(u);
        float2* col = L + j * 241;
#pragma unroll
        for (int i = 0; i < 3; ++i) col[15 * p + 3 * c + i] = u[i];
    }
    __syncthreads();
    for (int idx = tid; idx < 384; idx += 256) {
        int j = idx & 7, r = idx >> 3;
        s240_2a<+1>(L + j * 241, r / 3, r - 3 * (r / 3));
    }
    __syncthreads();
    for (int idx = tid; idx < 480; idx += 256) {
        int j = idx & 7, r = idx >> 3;
        s240_1b<+1>(L + j * 241, r >> 2, r & 3);
    }
    __syncthreads();
    for (int idx = tid; idx < 480; idx += 256) {
        int j = idx & 7, r = idx >> 3;
        s240_1a<+1>(L + j * 241, r >> 2, r & 3);
    }
    __syncthreads();
    for (int idx = tid; idx < 1920; idx += 256) {
        int n1 = idx >> 3, j = idx & 7;
        out[(size_t)b * NA + 200 * n1 + n20 + j] = L[j * 241 + n1].x;
    }
}

__global__ void init_kernel(float* __restrict__ acc, float* __restrict__ z0)
{
    int i = threadIdx.x;
    if (i < 64) { acc[i] = 0.f; z0[i] = 0.f; }
}

__global__ void finalize_scale(const float* __restrict__ acc, const float* __restrict__ z0,
                               float* __restrict__ scale)
{
    int b = threadIdx.x;
    if (b < 64) {
        float var = (acc[b] - z0[b] * z0[b]) / (48000.f * 47999.f);
        scale[b] = 0.1f / sqrtf(var);
    }
}

// ---------------- head ----------------
__global__ void head_kernel(const unsigned short* __restrict__ h3T, const float* __restrict__ w4,
                            const float* __restrict__ b4, float* __restrict__ control,
                            float* __restrict__ avg_shape, float* __restrict__ out_bf)
{
    __shared__ float w4s[40 * 64];
    __shared__ float b4s[40];
    __shared__ float sp[200 * 33];
    int b = blockIdx.x;
    for (int j = threadIdx.x; j < 40 * 64; j += 256) w4s[j] = w4[j];
    if (threadIdx.x < 40) b4s[threadIdx.x] = b4[threadIdx.x];
    __syncthreads();
    int t = threadIdx.x;
    if (t < 200) {
        float p[40];
#pragma unroll
        for (int o = 0; o < 40; ++o) p[o] = b4s[o];
        const unsigned short* hb = h3T + ((size_t)b * 200 + t) * 64;
        for (int i = 0; i < 64; ++i) {
            float h = bf2f(hb[i]);
#pragma unroll
            for (int o = 0; o < 40; ++o) p[o] += h * w4s[o * 64 + i];
        }
        float inh = 1.f / (1.f + expf(-p[0]));
        float exh = 1.f / (1.f + expf(-p[1]));
        float pr  = 1.f / (1.f + expf(-p[2]));
        float mx = p[3];
#pragma unroll
        for (int c = 1; c < 32; ++c) mx = fmaxf(mx, p[3 + c]);
        float e[32];
        float sum = 0.f;
#pragma unroll
        for (int c = 0; c < 32; ++c) { e[c] = expf(p[3 + c] - mx); sum += e[c]; }
        float inv = 1.f / sum;
#pragma unroll
        for (int c = 0; c < 32; ++c) sp[t * 33 + c] = e[c] * inv;
        float mx2 = p[35];
#pragma unroll
        for (int c = 1; c < 5; ++c) mx2 = fmaxf(mx2, p[35 + c]);
        float e2[5];
        float s2 = 0.f;
#pragma unroll
        for (int c = 0; c < 5; ++c) { e2[c] = expf(p[35 + c] - mx2); s2 += e2[c]; }
        float inv2 = 1.f / s2;
        float* ctl = control + (size_t)b * 8 * 200;
        ctl[0 * 200 + t] = inh;
        ctl[1 * 200 + t] = exh;
        ctl[2 * 200 + t] = pr;
#pragma unroll
        for (int c = 0; c < 5; ++c) ctl[(3 + c) * 200 + t] = e2[c] * inv2;
        float* bf = out_bf + (size_t)b * 3 * 200;
        bf[0 * 200 + t] = pr;
        bf[1 * 200 + t] = inh;
        bf[2 * 200 + t] = exh;
    }
    __syncthreads();
    if (t < 32) {
        float s = 0.f;
        for (int j = 0; j < 200; ++j) s += sp[j * 33 + t];
        avg_shape[b * 32 + t] = s * (1.f / 200.f);
    }
}

// ---------------- loc_w via precomputed interp weights (exact by linearity) ----------------
__global__ void wts_kernel(float* __restrict__ wts)
{
    __shared__ float w[200];
    int tid = threadIdx.x;
    for (int i = tid; i < 200; i += 256) w[i] = 0.f;
    __syncthreads();
    for (int i = tid; i < NA; i += 256) {
        float sf = (i + 0.5f) * (200.0f / 48000.0f) - 0.5f;
        sf = fminf(fmaxf(sf, 0.f), 199.f);
        int i0 = (int)sf;
        int i1 = min(i0 + 1, 199);
        float ww = sf - (float)i0;
        atomicAdd(&w[i0], 1.f - ww);
        atomicAdd(&w[i1], ww);
    }
    __syncthreads();
    for (int i = tid; i < 200; i += 256) wts[i] = w[i] * (1.f / 48000.f);
}

__global__ void locw2_kernel(const float* __restrict__ control, const float* __restrict__ wts,
                             float* __restrict__ loc_w)
{
    int c = blockIdx.x, b = blockIdx.y;
    int tid = threadIdx.x;
    const float* src = control + ((size_t)b * 8 + 3 + c) * 200;
    float s = (tid < 200) ? wts[tid] * src[tid] : 0.f;
    __shared__ float red[256];
    red[tid] = s;
    __syncthreads();
    for (int st = 128; st > 0; st >>= 1) {
        if (tid < st) red[tid] += red[tid + st];
        __syncthreads();
    }
    if (tid == 0) loc_w[b * 5 + c] = red[0];
}

__device__ inline float filter_shape_val(int c, int i)
{
    float lin = (float)i * (1.f / 31.f);
    if (c == 0) { float z = (lin - 0.2f) * 10.f;          return expf(-0.5f * z * z); }
    if (c == 1) { float z = (lin - 0.1f) * 10.f;          return expf(-0.5f * z * z); }
    if (c == 2) { float z = (lin - 0.4f) * (1.f / 0.15f); return expf(-0.5f * z * z); }
    if (c == 3) { float z = (lin - 0.6f) * 10.f;          return expf(-0.5f * z * z); }
    float v = 0.1f + 0.9f * lin;
    return v * v;
}

__global__ void fbins_kernel(float* __restrict__ fbins)
{
    int k = blockIdx.x * 256 + threadIdx.x;
    if (k >= NBINS) return;
    float sf = (k + 0.5f) * (32.0f / 24001.0f) - 0.5f;
    sf = fminf(fmaxf(sf, 0.f), 31.f);
    int i0 = (int)sf;
    int i1 = min(i0 + 1, 31);
    float w = sf - (float)i0;
#pragma unroll
    for (int c = 0; c < 5; ++c)
        fbins[c * NBINS + k] = filter_shape_val(c, i0) * (1.f - w) + filter_shape_val(c, i1) * w;
}

extern "C" void kernel_launch(void* const* d_in, const int* in_sizes, int n_in,
                              void* d_out, int out_size, void* d_ws, size_t ws_size,
                              hipStream_t stream)
{
    const float* cond = (const float*)d_in[0];
    const float* f0   = (const float*)d_in[1];
    const float* wn   = (const float*)d_in[2];
    const float* w1   = (const float*)d_in[3];
    const float* b1   = (const float*)d_in[4];
    const float* w2   = (const float*)d_in[5];
    const float* b2   = (const float*)d_in[6];
    const float* w3   = (const float*)d_in[7];
    const float* b3   = (const float*)d_in[8];
    const float* w4   = (const float*)d_in[9];
    const float* b4   = (const float*)d_in[10];

    float* out = (float*)d_out;
    float* filtered = out;
    float* bf_out   = out + (size_t)BB * NA;

    char* ws = (char*)d_ws;
    size_t off = 0;
    float2* I = (float2*)(ws + off);            off += 24576000;
    unsigned short* xpT1 = (unsigned short*)(ws + off); off += (size_t)BB * 212 * 160 * 2;
    unsigned short* xpT2 = (unsigned short*)(ws + off); off += (size_t)BB * 210 * 256 * 2;
    unsigned short* xpT3 = (unsigned short*)(ws + off); off += (size_t)BB * 210 * 128 * 2;
    unsigned short* xpT4 = (unsigned short*)(ws + off); off += (size_t)BB * 200 * 64 * 2;
    unsigned short* wT1  = (unsigned short*)(ws + off); off += (size_t)5 * 256 * 160 * 2;
    unsigned short* wT2  = (unsigned short*)(ws + off); off += (size_t)3 * 128 * 256 * 2;
    unsigned short* wT3  = (unsigned short*)(ws + off); off += (size_t)3 * 64 * 128 * 2;
    float* control   = (float*)(ws + off);
    float* avg_shape = control + 102400;
    float* loc_w     = avg_shape + 2048;
    float* acc       = loc_w + 320;
    float* z0        = acc + 64;
    float* scale     = z0 + 64;
    float* wts       = scale + 64;          // 200
    float* fbins     = wts + 256;

    dim3 blk(256);

    init_kernel<<<1, 64, 0, stream>>>(acc, z0);

    // prep
    {
        int n1 = BB * 212 * 160;
        prep_x1_kernel<<<dim3((n1 + 255) / 256), blk, 0, stream>>>(cond, f0, xpT1);
        int z2 = (BB * 210 * 256 * 2) / 16;
        zero16_kernel<<<dim3((z2 + 255) / 256), blk, 0, stream>>>((uint4*)xpT2, z2);
        int z3 = (BB * 210 * 128 * 2) / 16;
        zero16_kernel<<<dim3((z3 + 255) / 256), blk, 0, stream>>>((uint4*)xpT3, z3);
        prep_w_kernel<5, 129, 160, 256><<<dim3((5 * 256 * 160 + 255) / 256), blk, 0, stream>>>(w1, wT1);
        prep_w_kernel<3, 256, 256, 128><<<dim3((3 * 128 * 256 + 255) / 256), blk, 0, stream>>>(w2, wT2);
        prep_w_kernel<3, 128, 128, 64><<<dim3((3 * 64 * 128 + 255) / 256), blk, 0, stream>>>(w3, wT3);
        wts_kernel<<<1, 256, 0, stream>>>(wts);
    }

    // MFMA conv stack
    conv_mfma_kernel<4, 5, 5, 160, 256><<<dim3(13, BB), blk, 0, stream>>>(
        xpT1, 212, wT1, b1, xpT2, 210, 1);
    conv_mfma_kernel<2, 3, 8, 256, 128><<<dim3(13, BB), blk, 0, stream>>>(
        xpT2, 210, wT2, b2, xpT3, 210, 1);
    conv_mfma_kernel<1, 3, 4, 128, 64><<<dim3(13, BB), blk, 0, stream>>>(
        xpT3, 210, wT3, b3, xpT4, 200, 0);

    head_kernel<<<dim3(BB), blk, 0, stream>>>(xpT4, w4, b4, control, avg_shape, bf_out);
    locw2_kernel<<<dim3(5, BB), blk, 0, stream>>>(control, wts, loc_w);
    fbins_kernel<<<dim3((NBINS + 255) / 256), blk, 0, stream>>>(fbins);

    // fused four-step FFT pipeline (N = 240 x 200)
    passA_kernel<<<dim3(25, BB), blk, 0, stream>>>(wn, I);
    passB_kernel<0><<<dim3(24, BB), blk, 0, stream>>>(I, avg_shape, fbins, loc_w, acc, z0);
    finalize_scale<<<1, 64, 0, stream>>>(acc, z0, scale);
    passC_kernel<<<dim3(25, BB), blk, 0, stream>>>(I, control, f0, scale);
    passB_kernel<1><<<dim3(24, BB), blk, 0, stream>>>(I, avg_shape, fbins, loc_w, acc, z0);
    passD_kernel<<<dim3(25, BB), blk, 0, stream>>>(I, filtered);
}

// Round 9
// 422.394 us; speedup vs baseline: 1.3855x; 1.3855x over previous
//
#include <hip/hip_runtime.h>
#include <math.h>

#define BB 64
#define T_FR 200
#define NA 48000
#define NBINS 24001

typedef __attribute__((ext_vector_type(4))) float f32x4;
typedef __attribute__((ext_vector_type(8))) short bf16x8;

__device__ __forceinline__ unsigned short f2bf(float x)
{
    unsigned u = __float_as_uint(x);
    u = (u + 0x7FFFu + ((u >> 16) & 1u)) >> 16;
    return (unsigned short)u;
}
__device__ __forceinline__ float bf2f(unsigned short h)
{
    return __uint_as_float(((unsigned)h) << 16);
}

__device__ inline float2 cmul(float2 a, float2 b)
{
    return make_float2(a.x * b.x - a.y * b.y, a.x * b.y + a.y * b.x);
}

// e^{2*pi*i*rev} via HW transcendentals (args in revolutions)
__device__ __forceinline__ float2 cis_rev(float rev)
{
    return make_float2(__builtin_amdgcn_cosf(rev), __builtin_amdgcn_sinf(rev));
}

// ---------------- root tables ----------------
template<int R> __device__ __forceinline__ void fill_roots(float (&cr)[R], float (&si)[R]);
template<> __device__ __forceinline__ void fill_roots<3>(float (&cr)[3], float (&si)[3])
{
    const float S = 0.86602540378443865f;
    cr[0]=1.f; cr[1]=-0.5f; cr[2]=-0.5f;
    si[0]=0.f; si[1]=S;     si[2]=-S;
}
template<> __device__ __forceinline__ void fill_roots<4>(float (&cr)[4], float (&si)[4])
{
    cr[0]=1.f; cr[1]=0.f; cr[2]=-1.f; cr[3]=0.f;
    si[0]=0.f; si[1]=1.f; si[2]=0.f;  si[3]=-1.f;
}
template<> __device__ __forceinline__ void fill_roots<5>(float (&cr)[5], float (&si)[5])
{
    cr[0]=1.f; cr[1]=0.30901699437494742f; cr[2]=-0.80901699437494742f;
    cr[3]=-0.80901699437494742f; cr[4]=0.30901699437494742f;
    si[0]=0.f; si[1]=0.95105651629515357f; si[2]=0.58778525229247313f;
    si[3]=-0.58778525229247313f; si[4]=-0.95105651629515357f;
}
template<> __device__ __forceinline__ void fill_roots<8>(float (&cr)[8], float (&si)[8])
{
    const float C = 0.70710678118654752f;
    cr[0]=1.f; cr[1]=C;  cr[2]=0.f;  cr[3]=-C; cr[4]=-1.f; cr[5]=-C;  cr[6]=0.f;  cr[7]=C;
    si[0]=0.f; si[1]=C;  si[2]=1.f;  si[3]=C;  si[4]=0.f;  si[5]=-C;  si[6]=-1.f; si[7]=-C;
}

template<int S, int R>
__device__ __forceinline__ void dftR(float2 (&v)[R])
{
    float cr[R], si[R];
    fill_roots<R>(cr, si);
    float2 o[R];
#pragma unroll
    for (int k = 0; k < R; ++k) {
        float re = 0.f, im = 0.f;
#pragma unroll
        for (int j = 0; j < R; ++j) {
            int m = (j * k) % R;
            float ur = cr[m], ui = (S > 0) ? si[m] : -si[m];
            re += v[j].x * ur - v[j].y * ui;
            im += v[j].x * ui + v[j].y * ur;
        }
        o[k] = make_float2(re, im);
    }
#pragma unroll
    for (int k = 0; k < R; ++k) v[k] = o[k];
}

__device__ __constant__ float C25R[17] = {1.f,0.968583161f,0.876306680f,0.728968627f,0.535826795f,0.309016994f,0.062790520f,-0.187381315f,-0.425779292f,-0.637423990f,-0.809016994f,-0.929776486f,-0.992114701f,-0.992114701f,-0.929776486f,-0.809016994f,-0.637423990f};
__device__ __constant__ float C25I[17] = {0.f,0.248689887f,0.481753674f,0.684547106f,0.844327926f,0.951056516f,0.998026728f,0.982287251f,0.904827052f,0.770513243f,0.587785252f,0.368124553f,0.125333234f,-0.125333234f,-0.368124553f,-0.587785252f,-0.770513243f};
__device__ __constant__ float C15R[9] = {1.f,0.913545458f,0.669130606f,0.309016994f,-0.104528463f,-0.5f,-0.809016994f,-0.978147601f,-0.978147601f};
__device__ __constant__ float C15I[9] = {0.f,0.406736643f,0.743144825f,0.951056516f,0.994521895f,0.866025404f,0.587785252f,0.207911691f,-0.207911691f};
__device__ __constant__ float C16R[10] = {1.f,0.923879533f,0.707106781f,0.382683432f,0.f,-0.382683432f,-0.707106781f,-0.923879533f,-1.f,-0.923879533f};
__device__ __constant__ float C16I[10] = {0.f,0.382683432f,0.707106781f,0.923879533f,1.f,0.923879533f,0.707106781f,0.382683432f,0.f,-0.382683432f};

template<int S> __device__ __forceinline__ float2 tw25(int m){ return make_float2(C25R[m], S>0? C25I[m] : -C25I[m]); }
template<int S> __device__ __forceinline__ float2 tw15(int m){ return make_float2(C15R[m], S>0? C15I[m] : -C15I[m]); }
template<int S> __device__ __forceinline__ float2 tw16(int m){ return make_float2(C16R[m], S>0? C16I[m] : -C16I[m]); }

// ======== in-place micro-stages. Each item's read-set == write-set. ========
// --- 200 = 8 x (5 x 5), row slots: natural time at slot n ---
template<int SGN> __device__ __forceinline__ void s200_1(float2* row, int g)
{
    float2 v[8];
#pragma unroll
    for (int j = 0; j < 8; ++j) v[j] = row[25 * j + g];
    float gs = (float)(SGN * g) * (1.f / 200.f);
    if (SGN < 0) {
        dftR<-1, 8>(v);
#pragma unroll
        for (int k = 1; k < 8; ++k) v[k] = cmul(v[k], cis_rev(gs * (float)k));
    } else {
#pragma unroll
        for (int k = 1; k < 8; ++k) v[k] = cmul(v[k], cis_rev(gs * (float)k));
        dftR<+1, 8>(v);
    }
#pragma unroll
    for (int j = 0; j < 8; ++j) row[25 * j + g] = v[j];
}
template<int SGN> __device__ __forceinline__ void s200_2a(float2* row, int k1, int bq)
{
    float2 u[5];
    int base = 25 * k1 + bq;
#pragma unroll
    for (int a = 0; a < 5; ++a) u[a] = row[base + 5 * a];
    if (SGN < 0) {
        dftR<-1, 5>(u);
#pragma unroll
        for (int c = 1; c < 5; ++c) if (bq) u[c] = cmul(u[c], tw25<-1>(c * bq));
    } else {
#pragma unroll
        for (int c = 1; c < 5; ++c) if (bq) u[c] = cmul(u[c], tw25<+1>(c * bq));
        dftR<+1, 5>(u);
    }
#pragma unroll
    for (int c = 0; c < 5; ++c) row[base + 5 * c] = u[c];
}

// --- 240 = (4x4) x (5x3), column slots stride 1 ---
template<int SGN> __device__ __forceinline__ void s240_1a(float2* col, int g, int bq)
{
    float2 u[4];
#pragma unroll
    for (int a = 0; a < 4; ++a) u[a] = col[15 * (4 * a + bq) + g];
    if (SGN < 0) {
        dftR<-1, 4>(u);
#pragma unroll
        for (int c = 1; c < 4; ++c) if (bq) u[c] = cmul(u[c], tw16<-1>(c * bq));
    } else {
#pragma unroll
        for (int c = 1; c < 4; ++c) if (bq) u[c] = cmul(u[c], tw16<+1>(c * bq));
        dftR<+1, 4>(u);
    }
#pragma unroll
    for (int c = 0; c < 4; ++c) col[15 * (4 * c + bq) + g] = u[c];
}
template<int SGN> __device__ __forceinline__ void s240_1b(float2* col, int g, int c)
{
    float2 u[4];
    float gs = (float)(SGN * g) * (1.f / 240.f);
#pragma unroll
    for (int i = 0; i < 4; ++i) u[i] = col[15 * (4 * c + i) + g];
    if (SGN < 0) {
        dftR<-1, 4>(u);
#pragma unroll
        for (int d = 0; d < 4; ++d) { int k1 = c + 4 * d; if (k1) u[d] = cmul(u[d], cis_rev(gs * (float)k1)); }
    } else {
#pragma unroll
        for (int d = 0; d < 4; ++d) { int k1 = c + 4 * d; if (k1) u[d] = cmul(u[d], cis_rev(gs * (float)k1)); }
        dftR<+1, 4>(u);
    }
#pragma unroll
    for (int i = 0; i < 4; ++i) col[15 * (4 * c + i) + g] = u[i];
}
template<int SGN> __device__ __forceinline__ void s240_2a(float2* col, int p, int bq)
{
    float2 u[5];
    int base = 15 * p + bq;
#pragma unroll
    for (int a = 0; a < 5; ++a) u[a] = col[base + 3 * a];
    if (SGN < 0) {
        dftR<-1, 5>(u);
#pragma unroll
        for (int c = 1; c < 5; ++c) if (bq) u[c] = cmul(u[c], tw15<-1>(c * bq));
    } else {
#pragma unroll
        for (int c = 1; c < 5; ++c) if (bq) u[c] = cmul(u[c], tw15<+1>(c * bq));
        dftR<+1, 5>(u);
    }
#pragma unroll
    for (int c = 0; c < 5; ++c) col[base + 3 * c] = u[c];
}
__device__ __forceinline__ int p2k1(int p) { return ((p & 3) << 2) | (p >> 2); }

// ================= MFMA conv (unchanged, verified) =================
template<int NT, int TAPS, int CHUNKS, int CINP, int COUTP>
__global__ __launch_bounds__(256) void conv_mfma_kernel(
    const unsigned short* __restrict__ xT, int tRowsIn,
    const unsigned short* __restrict__ wT,
    const float* __restrict__ bias,
    unsigned short* __restrict__ outT, int tRowsOut, int tOffOut)
{
    const int b = blockIdx.y;
    const int t0 = blockIdx.x * 16;
    const int tid = threadIdx.x;
    const int wave = tid >> 6;
    const int lane = tid & 63;
    const int m = lane & 15;
    const int quad = lane >> 4;
    const int n0 = wave * (NT * 16);

    f32x4 acc[NT];
#pragma unroll
    for (int nt = 0; nt < NT; ++nt) acc[nt] = (f32x4){0.f, 0.f, 0.f, 0.f};

    const unsigned short* xb = xT + (size_t)b * tRowsIn * CINP;
#pragma unroll
    for (int kw = 0; kw < TAPS; ++kw) {
        const unsigned short* wk = wT + (size_t)kw * COUTP * CINP;
        const unsigned short* xrow = xb + (size_t)(t0 + kw + m) * CINP + quad * 8;
#pragma unroll
        for (int ch = 0; ch < CHUNKS; ++ch) {
            const int k0 = ch * 32;
            bf16x8 a = *(const bf16x8*)(xrow + k0);
#pragma unroll
            for (int nt = 0; nt < NT; ++nt) {
                bf16x8 bfr = *(const bf16x8*)(wk + (size_t)(n0 + nt * 16 + m) * CINP + k0 + quad * 8);
                acc[nt] = __builtin_amdgcn_mfma_f32_16x16x32_bf16(a, bfr, acc[nt], 0, 0, 0);
            }
        }
    }
#pragma unroll
    for (int nt = 0; nt < NT; ++nt) {
        const int n = n0 + nt * 16 + m;
        const float bz = bias[n];
#pragma unroll
        for (int r = 0; r < 4; ++r) {
            const int t = t0 + quad * 4 + r;
            if (t < 200) {
                float v = acc[nt][r] + bz;
                v = (v >= 0.f) ? v : 0.1f * v;
                outT[((size_t)b * tRowsOut + t + tOffOut) * COUTP + n] = f2bf(v);
            }
        }
    }
}

__global__ void prep_x1_kernel(const float* __restrict__ cond, const float* __restrict__ f0,
                               unsigned short* __restrict__ xpT1)
{
    int idx = blockIdx.x * 256 + threadIdx.x;
    const int total = BB * 212 * 160;
    if (idx >= total) return;
    int i = idx % 160;
    int rest = idx / 160;
    int tp = rest % 212;
    int b = rest / 212;
    int tt = tp - 2;
    float v = 0.f;
    if (tt >= 0 && tt < 200) {
        if (i < 128) v = cond[((size_t)b * 128 + i) * 200 + tt];
        else if (i == 128) v = (f0[b * 200 + tt] > 0.f) ? 1.f : 0.f;
    }
    xpT1[idx] = f2bf(v);
}

template<int TAPS, int CINR, int CINP, int COUTP>
__global__ void prep_w_kernel(const float* __restrict__ w, unsigned short* __restrict__ wT)
{
    int idx = blockIdx.x * 256 + threadIdx.x;
    const int total = TAPS * COUTP * CINP;
    if (idx >= total) return;
    int i = idx % CINP;
    int rest = idx / CINP;
    int o = rest % COUTP;
    int kw = rest / COUTP;
    float v = (i < CINR) ? w[((size_t)o * CINR + i) * TAPS + kw] : 0.f;
    wT[idx] = f2bf(v);
}

__global__ void zero16_kernel(uint4* __restrict__ p, int n16)
{
    int idx = blockIdx.x * 256 + threadIdx.x;
    if (idx < n16) p[idx] = make_uint4(0, 0, 0, 0);
}

// ================= FFT passes =================

// pass A: wn -> I[b][kg][n2] (8 columns/block, 25x64 grid)
__global__ __launch_bounds__(256) void passA_kernel(const float* __restrict__ wn,
                                                    float2* __restrict__ I)
{
    __shared__ float2 L[8 * 241];
    int b = blockIdx.y;
    int n20 = blockIdx.x * 8;
    int tid = threadIdx.x;
    for (int idx = tid; idx < 1920; idx += 256) {
        int n1 = idx >> 3, j = idx & 7;
        L[j * 241 + n1] = make_float2(wn[(size_t)b * NA + n1 * 200 + n20 + j], 0.f);
    }
    __syncthreads();
    for (int idx = tid; idx < 480; idx += 256) {
        int j = idx & 7, r = idx >> 3;
        s240_1a<-1>(L + j * 241, r >> 2, r & 3);
    }
    __syncthreads();
    for (int idx = tid; idx < 480; idx += 256) {
        int j = idx & 7, r = idx >> 3;
        s240_1b<-1>(L + j * 241, r >> 2, r & 3);
    }
    __syncthreads();
    for (int idx = tid; idx < 384; idx += 256) {
        int j = idx & 7, r = idx >> 3;
        s240_2a<-1>(L + j * 241, r / 3, r - 3 * (r / 3));
    }
    __syncthreads();
    for (int idx = tid; idx < 640; idx += 256) {
        int j = idx & 7, r = idx >> 3;
        int p = r / 5, c = r - 5 * p;
        float2* col = L + j * 241;
        float2 u[3];
#pragma unroll
        for (int i = 0; i < 3; ++i) u[i] = col[15 * p + 3 * c + i];
        dftR<-1, 3>(u);
        int k1 = p2k1(p);
        int n2 = n20 + j;
#pragma unroll
        for (int d = 0; d < 3; ++d) {
            int kg = k1 + 16 * (c + 5 * d);
            float2 tw = cis_rev(-(float)(n2 * kg) * (1.f / (float)NA));
            I[(size_t)b * NA + kg * 200 + n2] = cmul(u[d], tw);
        }
    }
}

// pass B: 10 rows/block (24x64 grid); fwd -> mul(+Parseval) -> inv, one LDS buffer
template<int MODE>
__global__ __launch_bounds__(256) void passB_kernel(float2* __restrict__ I,
    const float* __restrict__ avg_shape, const float* __restrict__ fbins,
    const float* __restrict__ loc_w, float* __restrict__ acc, float* __restrict__ z0)
{
    __shared__ float2 L[10 * 202];
    __shared__ float gsh[32];
    int b = blockIdx.y;
    int row0 = blockIdx.x * 10;
    int tid = threadIdx.x;
    if (MODE == 0) { if (tid < 32) gsh[tid] = avg_shape[b * 32 + tid]; }
    else           { if (tid < 5)  gsh[tid] = loc_w[b * 5 + tid]; }
    for (int idx = tid; idx < 2000; idx += 256) {
        int row = idx / 200, e = idx - row * 200;
        L[row * 202 + e] = I[(size_t)b * NA + (row0 + row) * 200 + e];
    }
    __syncthreads();
    for (int idx = tid; idx < 250; idx += 256) {
        int row = idx / 25, g = idx - row * 25;
        s200_1<-1>(L + row * 202, g);
    }
    __syncthreads();
    for (int idx = tid; idx < 400; idx += 256) {
        int row = idx / 40, r = idx - row * 40;
        s200_2a<-1>(L + row * 202, r / 5, r - 5 * (r / 5));
    }
    __syncthreads();
    float part = 0.f;
    for (int idx = tid; idx < 400; idx += 256) {
        int row = idx / 40, r = idx - row * 40;
        int k1r = r / 5, c = r - 5 * k1r;
        float2* rw = L + row * 202;
        int base = 25 * k1r + 5 * c;
        float2 u[5];
#pragma unroll
        for (int i = 0; i < 5; ++i) u[i] = rw[base + i];
        dftR<-1, 5>(u);
        int k1g = row0 + row;
#pragma unroll
        for (int d = 0; d < 5; ++d) {
            int k2 = k1r + 8 * (c + 5 * d);
            int k = k1g + 240 * k2;
            int kbin = min(k, NA - k);
            float2 X = u[d];
            if (MODE == 0) {
                int jj = (kbin * 32) / NBINS;
                if (jj < 31 && (NBINS * (jj + 1)) / 32 <= kbin) ++jj;
                float g2 = gsh[jj];
                float2 Z = make_float2(X.x * g2, X.y * g2);
                part += Z.x * Z.x + Z.y * Z.y;
                if (k == 0) z0[b] = Z.x;
                u[d] = make_float2(Z.x * (1.f / NA), Z.y * (1.f / NA));
            } else {
                float tf = 0.f;
#pragma unroll
                for (int cc = 0; cc < 5; ++cc) tf += gsh[cc] * fbins[cc * NBINS + kbin];
                tf *= (1.f / NA);
                u[d] = make_float2(X.x * tf, X.y * tf);
            }
        }
#pragma unroll
        for (int d = 0; d < 5; ++d) rw[base + d] = u[d];
    }
    if (MODE == 0) {
        for (int o = 32; o > 0; o >>= 1) part += __shfl_down(part, o);
        if ((tid & 63) == 0) atomicAdd(&acc[b], part);
    }
    __syncthreads();
    for (int idx = tid; idx < 400; idx += 256) {
        int row = idx / 40, r = idx - row * 40;
        int k1r = r / 5, c = r - 5 * k1r;
        float2* rw = L + row * 202;
        int base = 25 * k1r + 5 * c;
        float2 u[5];
#pragma unroll
        for (int i = 0; i < 5; ++i) u[i] = rw[base + i];
        dftR<+1, 5>(u);
#pragma unroll
        for (int i = 0; i < 5; ++i) rw[base + i] = u[i];
    }
    __syncthreads();
    for (int idx = tid; idx < 400; idx += 256) {
        int row = idx / 40, r = idx - row * 40;
        s200_2a<+1>(L + row * 202, r / 5, r - 5 * (r / 5));
    }
    __syncthreads();
    for (int idx = tid; idx < 250; idx += 256) {
        int row = idx / 25, g = idx - row * 25;
        s200_1<+1>(L + row * 202, g);
    }
    __syncthreads();
    for (int idx = tid; idx < 2000; idx += 256) {
        int row = idx / 200, n2 = idx - row * 200;
        int k1g = row0 + row;
        float2 tw = cis_rev((float)(n2 * k1g) * (1.f / (float)NA));
        I[(size_t)b * NA + k1g * 200 + n2] = cmul(L[row * 202 + n2], tw);
    }
}

// pass C: inv240 -> mod -> fwd240 (8 columns/block, 25x64 grid)
__global__ __launch_bounds__(256) void passC_kernel(float2* __restrict__ I,
    const float* __restrict__ control, const float* __restrict__ f0,
    const float* __restrict__ scale)
{
    __shared__ float2 L[8 * 241];
    __shared__ float ctl3[600];
    __shared__ float f0s[200];
    int b = blockIdx.y;
    int n20 = blockIdx.x * 8;
    int tid = threadIdx.x;
    for (int i = tid; i < 600; i += 256) ctl3[i] = control[(size_t)b * 1600 + i];
    for (int i = tid; i < 200; i += 256) f0s[i] = f0[b * 200 + i];
    for (int idx = tid; idx < 640; idx += 256) {
        int j = idx & 7, r = idx >> 3;
        int p = r / 5, c = r - 5 * p;
        int k1 = p2k1(p);
        int n2 = n20 + j;
        float2 u[3];
#pragma unroll
        for (int d = 0; d < 3; ++d) {
            int kg = k1 + 16 * (c + 5 * d);
            u[d] = I[(size_t)b * NA + kg * 200 + n2];
        }
        dftR<+1, 3>(u);
        float2* col = L + j * 241;
#pragma unroll
        for (int i = 0; i < 3; ++i) col[15 * p + 3 * c + i] = u[i];
    }
    __syncthreads();
    for (int idx = tid; idx < 384; idx += 256) {
        int j = idx & 7, r = idx >> 3;
        s240_2a<+1>(L + j * 241, r / 3, r - 3 * (r / 3));
    }
    __syncthreads();
    for (int idx = tid; idx < 480; idx += 256) {
        int j = idx & 7, r = idx >> 3;
        s240_1b<+1>(L + j * 241, r >> 2, r & 3);
    }
    __syncthreads();
    for (int idx = tid; idx < 480; idx += 256) {
        int j = idx & 7, r = idx >> 3;
        s240_1a<+1>(L + j * 241, r >> 2, r & 3);
    }
    __syncthreads();
    float sc = scale[b];
    for (int idx = tid; idx < 1920; idx += 256) {
        int n1 = idx >> 3, j = idx & 7;
        int n2 = n20 + j;
        int n = 200 * n1 + n2;
        float sf = ((float)n + 0.5f) * (1.f / 240.f) - 0.5f;
        sf = fminf(fmaxf(sf, 0.f), 199.f);
        int i0 = (int)sf;
        int i1 = min(i0 + 1, 199);
        float w = sf - (float)i0;
        float inh = ctl3[i0] * (1.f - w) + ctl3[i1] * w;
        float exh = ctl3[200 + i0] * (1.f - w) + ctl3[200 + i1] * w;
        float pr  = ctl3[400 + i0] * (1.f - w) + ctl3[400 + i1] * w;
        float v0 = f0s[i0] > 0.f ? 1.f : 0.f;
        float v1 = f0s[i1] > 0.f ? 1.f : 0.f;
        float vv = v0 * (1.f - w) + v1 * w;
        float m = inh * (1.f - vv) + exh * pr;
        float y = L[j * 241 + n1].x * sc;
        L[j * 241 + n1] = make_float2(y * m, 0.f);
    }
    __syncthreads();
    for (int idx = tid; idx < 480; idx += 256) {
        int j = idx & 7, r = idx >> 3;
        s240_1a<-1>(L + j * 241, r >> 2, r & 3);
    }
    __syncthreads();
    for (int idx = tid; idx < 480; idx += 256) {
        int j = idx & 7, r = idx >> 3;
        s240_1b<-1>(L + j * 241, r >> 2, r & 3);
    }
    __syncthreads();
    for (int idx = tid; idx < 384; idx += 256) {
        int j = idx & 7, r = idx >> 3;
        s240_2a<-1>(L + j * 241, r / 3, r - 3 * (r / 3));
    }
    __syncthreads();
    for (int idx = tid; idx < 640; idx += 256) {
        int j = idx & 7, r = idx >> 3;
        int p = r / 5, c = r - 5 * p;
        float2* col = L + j * 241;
        float2 u[3];
#pragma unroll
        for (int i = 0; i < 3; ++i) u[i] = col[15 * p + 3 * c + i];
        dftR<-1, 3>(u);
        int k1 = p2k1(p);
        int n2 = n20 + j;
#pragma unroll
        for (int d = 0; d < 3; ++d) {
            int kg = k1 + 16 * (c + 5 * d);
            float2 tw = cis_rev(-(float)(n2 * kg) * (1.f / (float)NA));
            I[(size_t)b * NA + kg * 200 + n2] = cmul(u[d], tw);
        }
    }
}

// pass D: inv240 -> real out
__global__ __launch_bounds__(256) void passD_kernel(const float2* __restrict__ I,
                                                    float* __restrict__ out)
{
    __shared__ float2 L[8 * 241];
    int b = blockIdx.y;
    int n20 = blockIdx.x * 8;
    int tid = threadIdx.x;
    for (int idx = tid; idx < 640; idx += 256) {
        int j = idx & 7, r = idx >> 3;
        int p = r / 5, c = r - 5 * p;
        int k1 = p2k1(p);
        int n2 = n20 + j;
        float2 u[3];
#pragma unroll
        for (int d = 0; d < 3; ++d) {
            int kg = k1 + 16 * (c + 5 * d);
            u[d] = I[(size_t)b * NA + kg * 200 + n2];
        }
        dftR<+1, 3>(u);
        float2* col = L + j * 241;
#pragma unroll
        for (int i = 0; i < 3; ++i) col[15 * p + 3 * c + i] = u[i];
    }
    __syncthreads();
    for (int idx = tid; idx < 384; idx += 256) {
        int j = idx & 7, r = idx >> 3;
        s240_2a<+1>(L + j * 241, r / 3, r - 3 * (r / 3));
    }
    __syncthreads();
    for (int idx = tid; idx < 480; idx += 256) {
        int j = idx & 7, r = idx >> 3;
        s240_1b<+1>(L + j * 241, r >> 2, r & 3);
    }
    __syncthreads();
    for (int idx = tid; idx < 480; idx += 256) {
        int j = idx & 7, r = idx >> 3;
        s240_1a<+1>(L + j * 241, r >> 2, r & 3);
    }
    __syncthreads();
    for (int idx = tid; idx < 1920; idx += 256) {
        int n1 = idx >> 3, j = idx & 7;
        out[(size_t)b * NA + 200 * n1 + n20 + j] = L[j * 241 + n1].x;
    }
}

__global__ void init_kernel(float* __restrict__ acc, float* __restrict__ z0)
{
    int i = threadIdx.x;
    if (i < 64) { acc[i] = 0.f; z0[i] = 0.f; }
}

__global__ void finalize_scale(const float* __restrict__ acc, const float* __restrict__ z0,
                               float* __restrict__ scale)
{
    int b = threadIdx.x;
    if (b < 64) {
        float var = (acc[b] - z0[b] * z0[b]) / (48000.f * 47999.f);
        scale[b] = 0.1f / sqrtf(var);
    }
}

// ---------------- head ----------------
__global__ void head_kernel(const unsigned short* __restrict__ h3T, const float* __restrict__ w4,
                            const float* __restrict__ b4, float* __restrict__ control,
                            float* __restrict__ avg_shape, float* __restrict__ out_bf)
{
    __shared__ float w4s[40 * 64];
    __shared__ float b4s[40];
    __shared__ float sp[200 * 33];
    int b = blockIdx.x;
    for (int j = threadIdx.x; j < 40 * 64; j += 256) w4s[j] = w4[j];
    if (threadIdx.x < 40) b4s[threadIdx.x] = b4[threadIdx.x];
    __syncthreads();
    int t = threadIdx.x;
    if (t < 200) {
        float p[40];
#pragma unroll
        for (int o = 0; o < 40; ++o) p[o] = b4s[o];
        const unsigned short* hb = h3T + ((size_t)b * 200 + t) * 64;
        for (int i = 0; i < 64; ++i) {
            float h = bf2f(hb[i]);
#pragma unroll
            for (int o = 0; o < 40; ++o) p[o] += h * w4s[o * 64 + i];
        }
        float inh = 1.f / (1.f + expf(-p[0]));
        float exh = 1.f / (1.f + expf(-p[1]));
        float pr  = 1.f / (1.f + expf(-p[2]));
        float mx = p[3];
#pragma unroll
        for (int c = 1; c < 32; ++c) mx = fmaxf(mx, p[3 + c]);
        float e[32];
        float sum = 0.f;
#pragma unroll
        for (int c = 0; c < 32; ++c) { e[c] = expf(p[3 + c] - mx); sum += e[c]; }
        float inv = 1.f / sum;
#pragma unroll
        for (int c = 0; c < 32; ++c) sp[t * 33 + c] = e[c] * inv;
        float mx2 = p[35];
#pragma unroll
        for (int c = 1; c < 5; ++c) mx2 = fmaxf(mx2, p[35 + c]);
        float e2[5];
        float s2 = 0.f;
#pragma unroll
        for (int c = 0; c < 5; ++c) { e2[c] = expf(p[35 + c] - mx2); s2 += e2[c]; }
        float inv2 = 1.f / s2;
        float* ctl = control + (size_t)b * 8 * 200;
        ctl[0 * 200 + t] = inh;
        ctl[1 * 200 + t] = exh;
        ctl[2 * 200 + t] = pr;
#pragma unroll
        for (int c = 0; c < 5; ++c) ctl[(3 + c) * 200 + t] = e2[c] * inv2;
        float* bf = out_bf + (size_t)b * 3 * 200;
        bf[0 * 200 + t] = pr;
        bf[1 * 200 + t] = inh;
        bf[2 * 200 + t] = exh;
    }
    __syncthreads();
    if (t < 32) {
        float s = 0.f;
        for (int j = 0; j < 200; ++j) s += sp[j * 33 + t];
        avg_shape[b * 32 + t] = s * (1.f / 200.f);
    }
}

// loc_w[b,c] = mean_t turb[b,c,t]  (interp weights are analytically uniform = 1/200)
__global__ void locw_mean_kernel(const float* __restrict__ control, float* __restrict__ loc_w)
{
    int c = blockIdx.x, b = blockIdx.y;
    int tid = threadIdx.x;
    const float* src = control + ((size_t)b * 8 + 3 + c) * 200;
    float s = (tid < 200) ? src[tid] : 0.f;
    for (int o = 32; o > 0; o >>= 1) s += __shfl_down(s, o);
    __shared__ float red[4];
    if ((tid & 63) == 0) red[tid >> 6] = s;
    __syncthreads();
    if (tid == 0) loc_w[b * 5 + c] = (red[0] + red[1] + red[2] + red[3]) * (1.f / 200.f);
}

__device__ inline float filter_shape_val(int c, int i)
{
    float lin = (float)i * (1.f / 31.f);
    if (c == 0) { float z = (lin - 0.2f) * 10.f;          return expf(-0.5f * z * z); }
    if (c == 1) { float z = (lin - 0.1f) * 10.f;          return expf(-0.5f * z * z); }
    if (c == 2) { float z = (lin - 0.4f) * (1.f / 0.15f); return expf(-0.5f * z * z); }
    if (c == 3) { float z = (lin - 0.6f) * 10.f;          return expf(-0.5f * z * z); }
    float v = 0.1f + 0.9f * lin;
    return v * v;
}

__global__ void fbins_kernel(float* __restrict__ fbins)
{
    int k = blockIdx.x * 256 + threadIdx.x;
    if (k >= NBINS) return;
    float sf = (k + 0.5f) * (32.0f / 24001.0f) - 0.5f;
    sf = fminf(fmaxf(sf, 0.f), 31.f);
    int i0 = (int)sf;
    int i1 = min(i0 + 1, 31);
    float w = sf - (float)i0;
#pragma unroll
    for (int c = 0; c < 5; ++c)
        fbins[c * NBINS + k] = filter_shape_val(c, i0) * (1.f - w) + filter_shape_val(c, i1) * w;
}

extern "C" void kernel_launch(void* const* d_in, const int* in_sizes, int n_in,
                              void* d_out, int out_size, void* d_ws, size_t ws_size,
                              hipStream_t stream)
{
    const float* cond = (const float*)d_in[0];
    const float* f0   = (const float*)d_in[1];
    const float* wn   = (const float*)d_in[2];
    const float* w1   = (const float*)d_in[3];
    const float* b1   = (const float*)d_in[4];
    const float* w2   = (const float*)d_in[5];
    const float* b2   = (const float*)d_in[6];
    const float* w3   = (const float*)d_in[7];
    const float* b3   = (const float*)d_in[8];
    const float* w4   = (const float*)d_in[9];
    const float* b4   = (const float*)d_in[10];

    float* out = (float*)d_out;
    float* filtered = out;
    float* bf_out   = out + (size_t)BB * NA;

    char* ws = (char*)d_ws;
    size_t off = 0;
    float2* I = (float2*)(ws + off);            off += 24576000;
    unsigned short* xpT1 = (unsigned short*)(ws + off); off += (size_t)BB * 212 * 160 * 2;
    unsigned short* xpT2 = (unsigned short*)(ws + off); off += (size_t)BB * 210 * 256 * 2;
    unsigned short* xpT3 = (unsigned short*)(ws + off); off += (size_t)BB * 210 * 128 * 2;
    unsigned short* xpT4 = (unsigned short*)(ws + off); off += (size_t)BB * 200 * 64 * 2;
    unsigned short* wT1  = (unsigned short*)(ws + off); off += (size_t)5 * 256 * 160 * 2;
    unsigned short* wT2  = (unsigned short*)(ws + off); off += (size_t)3 * 128 * 256 * 2;
    unsigned short* wT3  = (unsigned short*)(ws + off); off += (size_t)3 * 64 * 128 * 2;
    float* control   = (float*)(ws + off);
    float* avg_shape = control + 102400;
    float* loc_w     = avg_shape + 2048;
    float* acc       = loc_w + 320;
    float* z0        = acc + 64;
    float* scale     = z0 + 64;
    float* fbins     = scale + 64;

    dim3 blk(256);

    init_kernel<<<1, 64, 0, stream>>>(acc, z0);

    // prep
    {
        int n1 = BB * 212 * 160;
        prep_x1_kernel<<<dim3((n1 + 255) / 256), blk, 0, stream>>>(cond, f0, xpT1);
        int z2 = (BB * 210 * 256 * 2) / 16;
        zero16_kernel<<<dim3((z2 + 255) / 256), blk, 0, stream>>>((uint4*)xpT2, z2);
        int z3 = (BB * 210 * 128 * 2) / 16;
        zero16_kernel<<<dim3((z3 + 255) / 256), blk, 0, stream>>>((uint4*)xpT3, z3);
        prep_w_kernel<5, 129, 160, 256><<<dim3((5 * 256 * 160 + 255) / 256), blk, 0, stream>>>(w1, wT1);
        prep_w_kernel<3, 256, 256, 128><<<dim3((3 * 128 * 256 + 255) / 256), blk, 0, stream>>>(w2, wT2);
        prep_w_kernel<3, 128, 128, 64><<<dim3((3 * 64 * 128 + 255) / 256), blk, 0, stream>>>(w3, wT3);
    }

    // MFMA conv stack
    conv_mfma_kernel<4, 5, 5, 160, 256><<<dim3(13, BB), blk, 0, stream>>>(
        xpT1, 212, wT1, b1, xpT2, 210, 1);
    conv_mfma_kernel<2, 3, 8, 256, 128><<<dim3(13, BB), blk, 0, stream>>>(
        xpT2, 210, wT2, b2, xpT3, 210, 1);
    conv_mfma_kernel<1, 3, 4, 128, 64><<<dim3(13, BB), blk, 0, stream>>>(
        xpT3, 210, wT3, b3, xpT4, 200, 0);

    head_kernel<<<dim3(BB), blk, 0, stream>>>(xpT4, w4, b4, control, avg_shape, bf_out);
    locw_mean_kernel<<<dim3(5, BB), blk, 0, stream>>>(control, loc_w);
    fbins_kernel<<<dim3((NBINS + 255) / 256), blk, 0, stream>>>(fbins);

    // fused four-step FFT pipeline (N = 240 x 200)
    passA_kernel<<<dim3(25, BB), blk, 0, stream>>>(wn, I);
    passB_kernel<0><<<dim3(24, BB), blk, 0, stream>>>(I, avg_shape, fbins, loc_w, acc, z0);
    finalize_scale<<<1, 64, 0, stream>>>(acc, z0, scale);
    passC_kernel<<<dim3(25, BB), blk, 0, stream>>>(I, control, f0, scale);
    passB_kernel<1><<<dim3(24, BB), blk, 0, stream>>>(I, avg_shape, fbins, loc_w, acc, z0);
    passD_kernel<<<dim3(25, BB), blk, 0, stream>>>(I, filtered);
}

// Round 10
// 404.997 us; speedup vs baseline: 1.4450x; 1.0430x over previous
//
#include <hip/hip_runtime.h>
#include <math.h>

#define BB 64
#define T_FR 200
#define NA 48000
#define NBINS 24001

typedef __attribute__((ext_vector_type(4))) float f32x4;
typedef __attribute__((ext_vector_type(8))) short bf16x8;

__device__ __forceinline__ unsigned short f2bf(float x)
{
    unsigned u = __float_as_uint(x);
    u = (u + 0x7FFFu + ((u >> 16) & 1u)) >> 16;
    return (unsigned short)u;
}
__device__ __forceinline__ float bf2f(unsigned short h)
{
    return __uint_as_float(((unsigned)h) << 16);
}

__device__ inline float2 cmul(float2 a, float2 b)
{
    return make_float2(a.x * b.x - a.y * b.y, a.x * b.y + a.y * b.x);
}

__device__ __forceinline__ float2 cis_rev(float rev)
{
    return make_float2(__builtin_amdgcn_cosf(rev), __builtin_amdgcn_sinf(rev));
}

// ---------------- root tables ----------------
template<int R> __device__ __forceinline__ void fill_roots(float (&cr)[R], float (&si)[R]);
template<> __device__ __forceinline__ void fill_roots<3>(float (&cr)[3], float (&si)[3])
{
    const float S = 0.86602540378443865f;
    cr[0]=1.f; cr[1]=-0.5f; cr[2]=-0.5f;
    si[0]=0.f; si[1]=S;     si[2]=-S;
}
template<> __device__ __forceinline__ void fill_roots<4>(float (&cr)[4], float (&si)[4])
{
    cr[0]=1.f; cr[1]=0.f; cr[2]=-1.f; cr[3]=0.f;
    si[0]=0.f; si[1]=1.f; si[2]=0.f;  si[3]=-1.f;
}
template<> __device__ __forceinline__ void fill_roots<5>(float (&cr)[5], float (&si)[5])
{
    cr[0]=1.f; cr[1]=0.30901699437494742f; cr[2]=-0.80901699437494742f;
    cr[3]=-0.80901699437494742f; cr[4]=0.30901699437494742f;
    si[0]=0.f; si[1]=0.95105651629515357f; si[2]=0.58778525229247313f;
    si[3]=-0.58778525229247313f; si[4]=-0.95105651629515357f;
}
template<> __device__ __forceinline__ void fill_roots<8>(float (&cr)[8], float (&si)[8])
{
    const float C = 0.70710678118654752f;
    cr[0]=1.f; cr[1]=C;  cr[2]=0.f;  cr[3]=-C; cr[4]=-1.f; cr[5]=-C;  cr[6]=0.f;  cr[7]=C;
    si[0]=0.f; si[1]=C;  si[2]=1.f;  si[3]=C;  si[4]=0.f;  si[5]=-C;  si[6]=-1.f; si[7]=-C;
}

template<int S, int R>
__device__ __forceinline__ void dftR(float2 (&v)[R])
{
    float cr[R], si[R];
    fill_roots<R>(cr, si);
    float2 o[R];
#pragma unroll
    for (int k = 0; k < R; ++k) {
        float re = 0.f, im = 0.f;
#pragma unroll
        for (int j = 0; j < R; ++j) {
            int m = (j * k) % R;
            float ur = cr[m], ui = (S > 0) ? si[m] : -si[m];
            re += v[j].x * ur - v[j].y * ui;
            im += v[j].x * ui + v[j].y * ur;
        }
        o[k] = make_float2(re, im);
    }
#pragma unroll
    for (int k = 0; k < R; ++k) v[k] = o[k];
}

__device__ __constant__ float C25R[17] = {1.f,0.968583161f,0.876306680f,0.728968627f,0.535826795f,0.309016994f,0.062790520f,-0.187381315f,-0.425779292f,-0.637423990f,-0.809016994f,-0.929776486f,-0.992114701f,-0.992114701f,-0.929776486f,-0.809016994f,-0.637423990f};
__device__ __constant__ float C25I[17] = {0.f,0.248689887f,0.481753674f,0.684547106f,0.844327926f,0.951056516f,0.998026728f,0.982287251f,0.904827052f,0.770513243f,0.587785252f,0.368124553f,0.125333234f,-0.125333234f,-0.368124553f,-0.587785252f,-0.770513243f};
__device__ __constant__ float C15R[9] = {1.f,0.913545458f,0.669130606f,0.309016994f,-0.104528463f,-0.5f,-0.809016994f,-0.978147601f,-0.978147601f};
__device__ __constant__ float C15I[9] = {0.f,0.406736643f,0.743144825f,0.951056516f,0.994521895f,0.866025404f,0.587785252f,0.207911691f,-0.207911691f};
__device__ __constant__ float C16R[10] = {1.f,0.923879533f,0.707106781f,0.382683432f,0.f,-0.382683432f,-0.707106781f,-0.923879533f,-1.f,-0.923879533f};
__device__ __constant__ float C16I[10] = {0.f,0.382683432f,0.707106781f,0.923879533f,1.f,0.923879533f,0.707106781f,0.382683432f,0.f,-0.382683432f};

template<int S> __device__ __forceinline__ float2 tw25(int m){ return make_float2(C25R[m], S>0? C25I[m] : -C25I[m]); }
template<int S> __device__ __forceinline__ float2 tw15(int m){ return make_float2(C15R[m], S>0? C15I[m] : -C15I[m]); }
template<int S> __device__ __forceinline__ float2 tw16(int m){ return make_float2(C16R[m], S>0? C16I[m] : -C16I[m]); }

// ======== in-place micro-stages (read-set == write-set per item) ========
// --- 200 = 8 x (5 x 5) ---
template<int SGN> __device__ __forceinline__ void s200_1(float2* row, int g)
{
    float2 v[8];
#pragma unroll
    for (int j = 0; j < 8; ++j) v[j] = row[25 * j + g];
    float gs = (float)(SGN * g) * (1.f / 200.f);
    if (SGN < 0) {
        dftR<-1, 8>(v);
#pragma unroll
        for (int k = 1; k < 8; ++k) v[k] = cmul(v[k], cis_rev(gs * (float)k));
    } else {
#pragma unroll
        for (int k = 1; k < 8; ++k) v[k] = cmul(v[k], cis_rev(gs * (float)k));
        dftR<+1, 8>(v);
    }
#pragma unroll
    for (int j = 0; j < 8; ++j) row[25 * j + g] = v[j];
}
template<int SGN> __device__ __forceinline__ void s200_2a(float2* row, int k1, int bq)
{
    float2 u[5];
    int base = 25 * k1 + bq;
#pragma unroll
    for (int a = 0; a < 5; ++a) u[a] = row[base + 5 * a];
    if (SGN < 0) {
        dftR<-1, 5>(u);
#pragma unroll
        for (int c = 1; c < 5; ++c) if (bq) u[c] = cmul(u[c], tw25<-1>(c * bq));
    } else {
#pragma unroll
        for (int c = 1; c < 5; ++c) if (bq) u[c] = cmul(u[c], tw25<+1>(c * bq));
        dftR<+1, 5>(u);
    }
#pragma unroll
    for (int c = 0; c < 5; ++c) row[base + 5 * c] = u[c];
}
template<int SGN> __device__ __forceinline__ void s200_3(float2* row, int base)
{
    float2 u[5];
#pragma unroll
    for (int i = 0; i < 5; ++i) u[i] = row[base + i];
    dftR<SGN, 5>(u);
#pragma unroll
    for (int i = 0; i < 5; ++i) row[base + i] = u[i];
}
// full-spectrum slot for k2: slot = 25*(k2%8) + 5*((k2/8)%5) + (k2/40)
__device__ __forceinline__ int slot200(int k2)
{
    int A = k2 & 7;
    int r = k2 >> 3;
    return 25 * A + 5 * (r % 5) + (r / 5);
}

// --- 240 = (4x4) x (5x3) ---
template<int SGN> __device__ __forceinline__ void s240_1a(float2* col, int g, int bq)
{
    float2 u[4];
#pragma unroll
    for (int a = 0; a < 4; ++a) u[a] = col[15 * (4 * a + bq) + g];
    if (SGN < 0) {
        dftR<-1, 4>(u);
#pragma unroll
        for (int c = 1; c < 4; ++c) if (bq) u[c] = cmul(u[c], tw16<-1>(c * bq));
    } else {
#pragma unroll
        for (int c = 1; c < 4; ++c) if (bq) u[c] = cmul(u[c], tw16<+1>(c * bq));
        dftR<+1, 4>(u);
    }
#pragma unroll
    for (int c = 0; c < 4; ++c) col[15 * (4 * c + bq) + g] = u[c];
}
template<int SGN> __device__ __forceinline__ void s240_1b(float2* col, int g, int c)
{
    float2 u[4];
    float gs = (float)(SGN * g) * (1.f / 240.f);
#pragma unroll
    for (int i = 0; i < 4; ++i) u[i] = col[15 * (4 * c + i) + g];
    if (SGN < 0) {
        dftR<-1, 4>(u);
#pragma unroll
        for (int d = 0; d < 4; ++d) { int k1 = c + 4 * d; if (k1) u[d] = cmul(u[d], cis_rev(gs * (float)k1)); }
    } else {
#pragma unroll
        for (int d = 0; d < 4; ++d) { int k1 = c + 4 * d; if (k1) u[d] = cmul(u[d], cis_rev(gs * (float)k1)); }
        dftR<+1, 4>(u);
    }
#pragma unroll
    for (int i = 0; i < 4; ++i) col[15 * (4 * c + i) + g] = u[i];
}
template<int SGN> __device__ __forceinline__ void s240_2a(float2* col, int p, int bq)
{
    float2 u[5];
    int base = 15 * p + bq;
#pragma unroll
    for (int a = 0; a < 5; ++a) u[a] = col[base + 3 * a];
    if (SGN < 0) {
        dftR<-1, 5>(u);
#pragma unroll
        for (int c = 1; c < 5; ++c) if (bq) u[c] = cmul(u[c], tw15<-1>(c * bq));
    } else {
#pragma unroll
        for (int c = 1; c < 5; ++c) if (bq) u[c] = cmul(u[c], tw15<+1>(c * bq));
        dftR<+1, 5>(u);
    }
#pragma unroll
    for (int c = 0; c < 5; ++c) col[base + 3 * c] = u[c];
}
__device__ __forceinline__ int p2k1(int p) { return ((p & 3) << 2) | (p >> 2); }

// Hermitian pair combine: z = x1 + i x2 (x real). Given Za=Z[k], Zb=Z[N-k]:
// X1=(Za+conj(Zb))/2, X2=-i(Za-conj(Zb))/2; C=g1*X1+i*g2*X2 at k; Cp at N-k.
__device__ __forceinline__ void pair_combine(float2 Za, float2 Zb, float g1, float g2,
                                             float2& C, float2& Cp, float& e1, float& e2)
{
    float2 X1 = make_float2(0.5f * (Za.x + Zb.x), 0.5f * (Za.y - Zb.y));
    float2 w  = make_float2(0.5f * (Za.x - Zb.x), 0.5f * (Za.y + Zb.y));
    float2 X2 = make_float2(w.y, -w.x);
    float2 Z1 = make_float2(g1 * X1.x, g1 * X1.y);
    float2 Z2 = make_float2(g2 * X2.x, g2 * X2.y);
    e1 = Z1.x * Z1.x + Z1.y * Z1.y;
    e2 = Z2.x * Z2.x + Z2.y * Z2.y;
    C  = make_float2(Z1.x - Z2.y,  Z1.y + Z2.x);
    Cp = make_float2(Z1.x + Z2.y, -Z1.y + Z2.x);
}

// ================= MFMA conv (unchanged, verified) =================
template<int NT, int TAPS, int CHUNKS, int CINP, int COUTP>
__global__ __launch_bounds__(256) void conv_mfma_kernel(
    const unsigned short* __restrict__ xT, int tRowsIn,
    const unsigned short* __restrict__ wT,
    const float* __restrict__ bias,
    unsigned short* __restrict__ outT, int tRowsOut, int tOffOut)
{
    const int b = blockIdx.y;
    const int t0 = blockIdx.x * 16;
    const int tid = threadIdx.x;
    const int wave = tid >> 6;
    const int lane = tid & 63;
    const int m = lane & 15;
    const int quad = lane >> 4;
    const int n0 = wave * (NT * 16);

    f32x4 acc[NT];
#pragma unroll
    for (int nt = 0; nt < NT; ++nt) acc[nt] = (f32x4){0.f, 0.f, 0.f, 0.f};

    const unsigned short* xb = xT + (size_t)b * tRowsIn * CINP;
#pragma unroll
    for (int kw = 0; kw < TAPS; ++kw) {
        const unsigned short* wk = wT + (size_t)kw * COUTP * CINP;
        const unsigned short* xrow = xb + (size_t)(t0 + kw + m) * CINP + quad * 8;
#pragma unroll
        for (int ch = 0; ch < CHUNKS; ++ch) {
            const int k0 = ch * 32;
            bf16x8 a = *(const bf16x8*)(xrow + k0);
#pragma unroll
            for (int nt = 0; nt < NT; ++nt) {
                bf16x8 bfr = *(const bf16x8*)(wk + (size_t)(n0 + nt * 16 + m) * CINP + k0 + quad * 8);
                acc[nt] = __builtin_amdgcn_mfma_f32_16x16x32_bf16(a, bfr, acc[nt], 0, 0, 0);
            }
        }
    }
#pragma unroll
    for (int nt = 0; nt < NT; ++nt) {
        const int n = n0 + nt * 16 + m;
        const float bz = bias[n];
#pragma unroll
        for (int r = 0; r < 4; ++r) {
            const int t = t0 + quad * 4 + r;
            if (t < 200) {
                float v = acc[nt][r] + bz;
                v = (v >= 0.f) ? v : 0.1f * v;
                outT[((size_t)b * tRowsOut + t + tOffOut) * COUTP + n] = f2bf(v);
            }
        }
    }
}

__global__ void prep_x1_kernel(const float* __restrict__ cond, const float* __restrict__ f0,
                               unsigned short* __restrict__ xpT1)
{
    int idx = blockIdx.x * 256 + threadIdx.x;
    const int total = BB * 212 * 160;
    if (idx >= total) return;
    int i = idx % 160;
    int rest = idx / 160;
    int tp = rest % 212;
    int b = rest / 212;
    int tt = tp - 2;
    float v = 0.f;
    if (tt >= 0 && tt < 200) {
        if (i < 128) v = cond[((size_t)b * 128 + i) * 200 + tt];
        else if (i == 128) v = (f0[b * 200 + tt] > 0.f) ? 1.f : 0.f;
    }
    xpT1[idx] = f2bf(v);
}

template<int TAPS, int CINR, int CINP, int COUTP>
__global__ void prep_w_kernel(const float* __restrict__ w, unsigned short* __restrict__ wT)
{
    int idx = blockIdx.x * 256 + threadIdx.x;
    const int total = TAPS * COUTP * CINP;
    if (idx >= total) return;
    int i = idx % CINP;
    int rest = idx / CINP;
    int o = rest % COUTP;
    int kw = rest / COUTP;
    float v = (i < CINR) ? w[((size_t)o * CINR + i) * TAPS + kw] : 0.f;
    wT[idx] = f2bf(v);
}

__global__ void zero16_kernel(uint4* __restrict__ p, int n16)
{
    int idx = blockIdx.x * 256 + threadIdx.x;
    if (idx < n16) p[idx] = make_uint4(0, 0, 0, 0);
}

// ================= FFT passes (batch-paired: q handles batches 2q, 2q+1) =================

// pass A: z = wn[2q] + i wn[2q+1] -> I[q][kg][n2]  (4 columns/block, 50x32 grid)
__global__ __launch_bounds__(256) void passA_kernel(const float* __restrict__ wn,
                                                    float2* __restrict__ I)
{
    __shared__ float2 L[4 * 241];
    int q = blockIdx.y;
    const float* w1p = wn + (size_t)(2 * q) * NA;
    const float* w2p = wn + (size_t)(2 * q + 1) * NA;
    int n20 = blockIdx.x * 4;
    int tid = threadIdx.x;
    for (int idx = tid; idx < 960; idx += 256) {
        int n1 = idx >> 2, j = idx & 3;
        int n = n1 * 200 + n20 + j;
        L[j * 241 + n1] = make_float2(w1p[n], w2p[n]);
    }
    __syncthreads();
    for (int idx = tid; idx < 240; idx += 256) {
        int j = idx & 3, r = idx >> 2;
        s240_1a<-1>(L + j * 241, r >> 2, r & 3);
    }
    __syncthreads();
    for (int idx = tid; idx < 240; idx += 256) {
        int j = idx & 3, r = idx >> 2;
        s240_1b<-1>(L + j * 241, r >> 2, r & 3);
    }
    __syncthreads();
    for (int idx = tid; idx < 192; idx += 256) {
        int j = idx & 3, r = idx >> 2;
        s240_2a<-1>(L + j * 241, r / 3, r - 3 * (r / 3));
    }
    __syncthreads();
    for (int idx = tid; idx < 320; idx += 256) {
        int j = idx & 3, r = idx >> 2;
        int p = r / 5, c = r - 5 * p;
        float2* col = L + j * 241;
        float2 u[3];
#pragma unroll
        for (int i = 0; i < 3; ++i) u[i] = col[15 * p + 3 * c + i];
        dftR<-1, 3>(u);
        int k1 = p2k1(p);
        int n2 = n20 + j;
#pragma unroll
        for (int d = 0; d < 3; ++d) {
            int kg = k1 + 16 * (c + 5 * d);
            float2 tw = cis_rev(-(float)(n2 * kg) * (1.f / (float)NA));
            I[(size_t)q * NA + kg * 200 + n2] = cmul(u[d], tw);
        }
    }
}

// pass B (paired): 3 conjugate row-pairs per block (40x32 grid).
// fwd fft200 on 6 rows -> Hermitian split + per-batch gains (+Parseval MODE0) -> inv fft200 -> tw.
template<int MODE>
__global__ __launch_bounds__(256) void passBp_kernel(float2* __restrict__ I,
    const float* __restrict__ avg_shape, const float* __restrict__ fbins,
    const float* __restrict__ loc_w, float* __restrict__ acc, float* __restrict__ z0)
{
    __shared__ float2 L[6 * 202];
    __shared__ float g1sh[32], g2sh[32];
    int q = blockIdx.y;
    int b1 = 2 * q, b2 = 2 * q + 1;
    int bx = blockIdx.x;
    int tid = threadIdx.x;
    if (MODE == 0) {
        if (tid < 32) { g1sh[tid] = avg_shape[b1 * 32 + tid]; g2sh[tid] = avg_shape[b2 * 32 + tid]; }
    } else {
        if (tid < 5) { g1sh[tid] = loc_w[b1 * 5 + tid]; g2sh[tid] = loc_w[b2 * 5 + tid]; }
    }
    // row map: slot s -> global row R
    int Rrow[6];
#pragma unroll
    for (int s = 0; s < 6; ++s) {
        int p = s >> 1;
        int pi = 3 * bx + p;
        Rrow[s] = (pi == 0) ? ((s & 1) ? 120 : 0) : ((s & 1) ? 240 - pi : pi);
    }
    for (int idx = tid; idx < 1200; idx += 256) {
        int s = idx / 200, e = idx - s * 200;
        L[s * 202 + e] = I[(size_t)q * NA + Rrow[s] * 200 + e];
    }
    __syncthreads();
    for (int idx = tid; idx < 150; idx += 256) {
        int s = idx / 25, g = idx - s * 25;
        s200_1<-1>(L + s * 202, g);
    }
    __syncthreads();
    for (int idx = tid; idx < 240; idx += 256) {
        int s = idx / 40, r = idx - s * 40;
        s200_2a<-1>(L + s * 202, r / 5, r - 5 * (r / 5));
    }
    __syncthreads();
    for (int idx = tid; idx < 240; idx += 256) {
        int s = idx / 40, r = idx - s * 40;
        s200_3<-1>(L + s * 202, 25 * (r / 5) + 5 * (r - 5 * (r / 5)));
    }
    __syncthreads();
    // Hermitian combine at full-spectrum points
    float part1 = 0.f, part2 = 0.f;
    for (int idx = tid; idx < 603; idx += 256) {
        int p = idx / 201, t = idx - p * 201;
        int pi = 3 * bx + p;
        float2* rwA = L + (2 * p) * 202;
        float2* rwB = L + (2 * p + 1) * 202;
        int k = -1;                  // spectrum index of the "a" point
        float2 Za, Zb;
        int sa = 0, sb = 0;          // slots to write C, Cp
        float2* wa = rwA; float2* wb = rwB;
        bool self1 = false;          // single self-conjugate point
        if (pi != 0) {
            if (t >= 200) continue;
            int k2 = t, k2p = 199 - t;
            sa = slot200(k2); sb = slot200(k2p);
            Za = rwA[sa]; Zb = rwB[sb];
            k = pi + 240 * k2;
        } else if (t < 101) {
            // row 0: partner within row 0 at k2' = (200 - k2) % 200
            wa = rwA; wb = rwA;
            if (t == 0 || t == 100) {
                sa = slot200(t); sb = sa;
                Za = rwA[sa]; Zb = Za;   // self: X1 = Re, X2 = Im handled by formulas
                k = 240 * t;
                self1 = true;
            } else {
                sa = slot200(t); sb = slot200(200 - t);
                Za = rwA[sa]; Zb = rwA[sb];
                k = 240 * t;
            }
        } else {
            // row 120: t2 in [0,100), partner 199 - t2 within row 120
            int t2 = t - 101;
            if (t2 >= 100) continue;
            wa = rwB; wb = rwB;
            sa = slot200(t2); sb = slot200(199 - t2);
            Za = rwB[sa]; Zb = rwB[sb];
            k = 120 + 240 * t2;
        }
        int kbin = min(k, NA - k);
        float g1, g2;
        if (MODE == 0) {
            int jj = (kbin * 32) / NBINS;
            if (jj < 31 && (NBINS * (jj + 1)) / 32 <= kbin) ++jj;
            g1 = g1sh[jj]; g2 = g2sh[jj];
        } else {
            g1 = 0.f; g2 = 0.f;
#pragma unroll
            for (int c = 0; c < 5; ++c) {
                float fb = fbins[c * NBINS + kbin];
                g1 += g1sh[c] * fb; g2 += g2sh[c] * fb;
            }
        }
        float2 C, Cp; float e1, e2;
        pair_combine(Za, Zb, g1, g2, C, Cp, e1, e2);
        if (MODE == 0) {
            float wgt = self1 ? 1.f : 2.f;
            part1 += wgt * e1; part2 += wgt * e2;
            if (k == 0) { z0[b1] = g1 * Za.x; z0[b2] = g2 * Za.y; }
        }
        wa[sa] = make_float2(C.x * (1.f / NA), C.y * (1.f / NA));
        if (!self1) wb[sb] = make_float2(Cp.x * (1.f / NA), Cp.y * (1.f / NA));
    }
    if (MODE == 0) {
        for (int o = 32; o > 0; o >>= 1) {
            part1 += __shfl_down(part1, o);
            part2 += __shfl_down(part2, o);
        }
        if ((tid & 63) == 0) { atomicAdd(&acc[b1], part1); atomicAdd(&acc[b2], part2); }
    }
    __syncthreads();
    for (int idx = tid; idx < 240; idx += 256) {
        int s = idx / 40, r = idx - s * 40;
        s200_3<+1>(L + s * 202, 25 * (r / 5) + 5 * (r - 5 * (r / 5)));
    }
    __syncthreads();
    for (int idx = tid; idx < 240; idx += 256) {
        int s = idx / 40, r = idx - s * 40;
        s200_2a<+1>(L + s * 202, r / 5, r - 5 * (r / 5));
    }
    __syncthreads();
    for (int idx = tid; idx < 150; idx += 256) {
        int s = idx / 25, g = idx - s * 25;
        s200_1<+1>(L + s * 202, g);
    }
    __syncthreads();
    for (int idx = tid; idx < 1200; idx += 256) {
        int s = idx / 200, n2 = idx - s * 200;
        int k1g = Rrow[s];
        float2 tw = cis_rev((float)(n2 * k1g) * (1.f / (float)NA));
        I[(size_t)q * NA + k1g * 200 + n2] = cmul(L[s * 202 + n2], tw);
    }
}

// pass C: inv240 -> per-batch scale*mod on (re,im) -> fwd240 (4 columns/block, 50x32)
__global__ __launch_bounds__(256) void passC_kernel(float2* __restrict__ I,
    const float* __restrict__ control, const float* __restrict__ f0,
    const float* __restrict__ scale)
{
    __shared__ float2 L[4 * 241];
    __shared__ float ctlA[600], ctlB[600];
    __shared__ float f0A[200], f0B[200];
    int q = blockIdx.y;
    int b1 = 2 * q, b2 = 2 * q + 1;
    int n20 = blockIdx.x * 4;
    int tid = threadIdx.x;
    for (int i = tid; i < 600; i += 256) {
        ctlA[i] = control[(size_t)b1 * 1600 + i];
        ctlB[i] = control[(size_t)b2 * 1600 + i];
    }
    for (int i = tid; i < 200; i += 256) {
        f0A[i] = f0[b1 * 200 + i];
        f0B[i] = f0[b2 * 200 + i];
    }
    for (int idx = tid; idx < 320; idx += 256) {
        int j = idx & 3, r = idx >> 2;
        int p = r / 5, c = r - 5 * p;
        int k1 = p2k1(p);
        int n2 = n20 + j;
        float2 u[3];
#pragma unroll
        for (int d = 0; d < 3; ++d) {
            int kg = k1 + 16 * (c + 5 * d);
            u[d] = I[(size_t)q * NA + kg * 200 + n2];
        }
        dftR<+1, 3>(u);
        float2* col = L + j * 241;
#pragma unroll
        for (int i = 0; i < 3; ++i) col[15 * p + 3 * c + i] = u[i];
    }
    __syncthreads();
    for (int idx = tid; idx < 192; idx += 256) {
        int j = idx & 3, r = idx >> 2;
        s240_2a<+1>(L + j * 241, r / 3, r - 3 * (r / 3));
    }
    __syncthreads();
    for (int idx = tid; idx < 240; idx += 256) {
        int j = idx & 3, r = idx >> 2;
        s240_1b<+1>(L + j * 241, r >> 2, r & 3);
    }
    __syncthreads();
    for (int idx = tid; idx < 240; idx += 256) {
        int j = idx & 3, r = idx >> 2;
        s240_1a<+1>(L + j * 241, r >> 2, r & 3);
    }
    __syncthreads();
    float sc1 = scale[b1], sc2 = scale[b2];
    for (int idx = tid; idx < 960; idx += 256) {
        int n1 = idx >> 2, j = idx & 3;
        int n2 = n20 + j;
        int n = 200 * n1 + n2;
        float sf = ((float)n + 0.5f) * (1.f / 240.f) - 0.5f;
        sf = fminf(fmaxf(sf, 0.f), 199.f);
        int i0 = (int)sf;
        int i1 = min(i0 + 1, 199);
        float w = sf - (float)i0;
        float w0 = 1.f - w;
        // batch 1
        float inh = ctlA[i0] * w0 + ctlA[i1] * w;
        float exh = ctlA[200 + i0] * w0 + ctlA[200 + i1] * w;
        float pr  = ctlA[400 + i0] * w0 + ctlA[400 + i1] * w;
        float vv  = (f0A[i0] > 0.f ? 1.f : 0.f) * w0 + (f0A[i1] > 0.f ? 1.f : 0.f) * w;
        float m1 = inh * (1.f - vv) + exh * pr;
        // batch 2
        inh = ctlB[i0] * w0 + ctlB[i1] * w;
        exh = ctlB[200 + i0] * w0 + ctlB[200 + i1] * w;
        pr  = ctlB[400 + i0] * w0 + ctlB[400 + i1] * w;
        vv  = (f0B[i0] > 0.f ? 1.f : 0.f) * w0 + (f0B[i1] > 0.f ? 1.f : 0.f) * w;
        float m2 = inh * (1.f - vv) + exh * pr;
        float2 z = L[j * 241 + n1];
        L[j * 241 + n1] = make_float2(z.x * sc1 * m1, z.y * sc2 * m2);
    }
    __syncthreads();
    for (int idx = tid; idx < 240; idx += 256) {
        int j = idx & 3, r = idx >> 2;
        s240_1a<-1>(L + j * 241, r >> 2, r & 3);
    }
    __syncthreads();
    for (int idx = tid; idx < 240; idx += 256) {
        int j = idx & 3, r = idx >> 2;
        s240_1b<-1>(L + j * 241, r >> 2, r & 3);
    }
    __syncthreads();
    for (int idx = tid; idx < 192; idx += 256) {
        int j = idx & 3, r = idx >> 2;
        s240_2a<-1>(L + j * 241, r / 3, r - 3 * (r / 3));
    }
    __syncthreads();
    for (int idx = tid; idx < 320; idx += 256) {
        int j = idx & 3, r = idx >> 2;
        int p = r / 5, c = r - 5 * p;
        float2* col = L + j * 241;
        float2 u[3];
#pragma unroll
        for (int i = 0; i < 3; ++i) u[i] = col[15 * p + 3 * c + i];
        dftR<-1, 3>(u);
        int k1 = p2k1(p);
        int n2 = n20 + j;
#pragma unroll
        for (int d = 0; d < 3; ++d) {
            int kg = k1 + 16 * (c + 5 * d);
            float2 tw = cis_rev(-(float)(n2 * kg) * (1.f / (float)NA));
            I[(size_t)q * NA + kg * 200 + n2] = cmul(u[d], tw);
        }
    }
}

// pass D: inv240 -> two real outputs
__global__ __launch_bounds__(256) void passD_kernel(const float2* __restrict__ I,
                                                    float* __restrict__ out)
{
    __shared__ float2 L[4 * 241];
    int q = blockIdx.y;
    int b1 = 2 * q, b2 = 2 * q + 1;
    int n20 = blockIdx.x * 4;
    int tid = threadIdx.x;
    for (int idx = tid; idx < 320; idx += 256) {
        int j = idx & 3, r = idx >> 2;
        int p = r / 5, c = r - 5 * p;
        int k1 = p2k1(p);
        int n2 = n20 + j;
        float2 u[3];
#pragma unroll
        for (int d = 0; d < 3; ++d) {
            int kg = k1 + 16 * (c + 5 * d);
            u[d] = I[(size_t)q * NA + kg * 200 + n2];
        }
        dftR<+1, 3>(u);
        float2* col = L + j * 241;
#pragma unroll
        for (int i = 0; i < 3; ++i) col[15 * p + 3 * c + i] = u[i];
    }
    __syncthreads();
    for (int idx = tid; idx < 192; idx += 256) {
        int j = idx & 3, r = idx >> 2;
        s240_2a<+1>(L + j * 241, r / 3, r - 3 * (r / 3));
    }
    __syncthreads();
    for (int idx = tid; idx < 240; idx += 256) {
        int j = idx & 3, r = idx >> 2;
        s240_1b<+1>(L + j * 241, r >> 2, r & 3);
    }
    __syncthreads();
    for (int idx = tid; idx < 240; idx += 256) {
        int j = idx & 3, r = idx >> 2;
        s240_1a<+1>(L + j * 241, r >> 2, r & 3);
    }
    __syncthreads();
    for (int idx = tid; idx < 960; idx += 256) {
        int n1 = idx >> 2, j = idx & 3;
        int n = 200 * n1 + n20 + j;
        float2 z = L[j * 241 + n1];
        out[(size_t)b1 * NA + n] = z.x;
        out[(size_t)b2 * NA + n] = z.y;
    }
}

__global__ void init_kernel(float* __restrict__ acc, float* __restrict__ z0)
{
    int i = threadIdx.x;
    if (i < 64) { acc[i] = 0.f; z0[i] = 0.f; }
}

__global__ void finalize_scale(const float* __restrict__ acc, const float* __restrict__ z0,
                               float* __restrict__ scale)
{
    int b = threadIdx.x;
    if (b < 64) {
        float var = (acc[b] - z0[b] * z0[b]) / (48000.f * 47999.f);
        scale[b] = 0.1f / sqrtf(var);
    }
}

// ---------------- head ----------------
__global__ void head_kernel(const unsigned short* __restrict__ h3T, const float* __restrict__ w4,
                            const float* __restrict__ b4, float* __restrict__ control,
                            float* __restrict__ avg_shape, float* __restrict__ out_bf)
{
    __shared__ float w4s[40 * 64];
    __shared__ float b4s[40];
    __shared__ float sp[200 * 33];
    int b = blockIdx.x;
    for (int j = threadIdx.x; j < 40 * 64; j += 256) w4s[j] = w4[j];
    if (threadIdx.x < 40) b4s[threadIdx.x] = b4[threadIdx.x];
    __syncthreads();
    int t = threadIdx.x;
    if (t < 200) {
        float p[40];
#pragma unroll
        for (int o = 0; o < 40; ++o) p[o] = b4s[o];
        const unsigned short* hb = h3T + ((size_t)b * 200 + t) * 64;
        for (int i = 0; i < 64; ++i) {
            float h = bf2f(hb[i]);
#pragma unroll
            for (int o = 0; o < 40; ++o) p[o] += h * w4s[o * 64 + i];
        }
        float inh = 1.f / (1.f + expf(-p[0]));
        float exh = 1.f / (1.f + expf(-p[1]));
        float pr  = 1.f / (1.f + expf(-p[2]));
        float mx = p[3];
#pragma unroll
        for (int c = 1; c < 32; ++c) mx = fmaxf(mx, p[3 + c]);
        float e[32];
        float sum = 0.f;
#pragma unroll
        for (int c = 0; c < 32; ++c) { e[c] = expf(p[3 + c] - mx); sum += e[c]; }
        float inv = 1.f / sum;
#pragma unroll
        for (int c = 0; c < 32; ++c) sp[t * 33 + c] = e[c] * inv;
        float mx2 = p[35];
#pragma unroll
        for (int c = 1; c < 5; ++c) mx2 = fmaxf(mx2, p[35 + c]);
        float e2[5];
        float s2 = 0.f;
#pragma unroll
        for (int c = 0; c < 5; ++c) { e2[c] = expf(p[35 + c] - mx2); s2 += e2[c]; }
        float inv2 = 1.f / s2;
        float* ctl = control + (size_t)b * 8 * 200;
        ctl[0 * 200 + t] = inh;
        ctl[1 * 200 + t] = exh;
        ctl[2 * 200 + t] = pr;
#pragma unroll
        for (int c = 0; c < 5; ++c) ctl[(3 + c) * 200 + t] = e2[c] * inv2;
        float* bf = out_bf + (size_t)b * 3 * 200;
        bf[0 * 200 + t] = pr;
        bf[1 * 200 + t] = inh;
        bf[2 * 200 + t] = exh;
    }
    __syncthreads();
    if (t < 32) {
        float s = 0.f;
        for (int j = 0; j < 200; ++j) s += sp[j * 33 + t];
        avg_shape[b * 32 + t] = s * (1.f / 200.f);
    }
}

// loc_w[b,c] = mean_t turb[b,c,t] (interp weights analytically uniform = 1/200)
__global__ void locw_mean_kernel(const float* __restrict__ control, float* __restrict__ loc_w)
{
    int c = blockIdx.x, b = blockIdx.y;
    int tid = threadIdx.x;
    const float* src = control + ((size_t)b * 8 + 3 + c) * 200;
    float s = (tid < 200) ? src[tid] : 0.f;
    for (int o = 32; o > 0; o >>= 1) s += __shfl_down(s, o);
    __shared__ float red[4];
    if ((tid & 63) == 0) red[tid >> 6] = s;
    __syncthreads();
    if (tid == 0) loc_w[b * 5 + c] = (red[0] + red[1] + red[2] + red[3]) * (1.f / 200.f);
}

__device__ inline float filter_shape_val(int c, int i)
{
    float lin = (float)i * (1.f / 31.f);
    if (c == 0) { float z = (lin - 0.2f) * 10.f;          return expf(-0.5f * z * z); }
    if (c == 1) { float z = (lin - 0.1f) * 10.f;          return expf(-0.5f * z * z); }
    if (c == 2) { float z = (lin - 0.4f) * (1.f / 0.15f); return expf(-0.5f * z * z); }
    if (c == 3) { float z = (lin - 0.6f) * 10.f;          return expf(-0.5f * z * z); }
    float v = 0.1f + 0.9f * lin;
    return v * v;
}

__global__ void fbins_kernel(float* __restrict__ fbins)
{
    int k = blockIdx.x * 256 + threadIdx.x;
    if (k >= NBINS) return;
    float sf = (k + 0.5f) * (32.0f / 24001.0f) - 0.5f;
    sf = fminf(fmaxf(sf, 0.f), 31.f);
    int i0 = (int)sf;
    int i1 = min(i0 + 1, 31);
    float w = sf - (float)i0;
#pragma unroll
    for (int c = 0; c < 5; ++c)
        fbins[c * NBINS + k] = filter_shape_val(c, i0) * (1.f - w) + filter_shape_val(c, i1) * w;
}

extern "C" void kernel_launch(void* const* d_in, const int* in_sizes, int n_in,
                              void* d_out, int out_size, void* d_ws, size_t ws_size,
                              hipStream_t stream)
{
    const float* cond = (const float*)d_in[0];
    const float* f0   = (const float*)d_in[1];
    const float* wn   = (const float*)d_in[2];
    const float* w1   = (const float*)d_in[3];
    const float* b1   = (const float*)d_in[4];
    const float* w2   = (const float*)d_in[5];
    const float* b2   = (const float*)d_in[6];
    const float* w3   = (const float*)d_in[7];
    const float* b3   = (const float*)d_in[8];
    const float* w4   = (const float*)d_in[9];
    const float* b4   = (const float*)d_in[10];

    float* out = (float*)d_out;
    float* filtered = out;
    float* bf_out   = out + (size_t)BB * NA;

    char* ws = (char*)d_ws;
    size_t off = 0;
    float2* I = (float2*)(ws + off);            off += 24576000;   // only 32*NA*8 used now
    unsigned short* xpT1 = (unsigned short*)(ws + off); off += (size_t)BB * 212 * 160 * 2;
    unsigned short* xpT2 = (unsigned short*)(ws + off); off += (size_t)BB * 210 * 256 * 2;
    unsigned short* xpT3 = (unsigned short*)(ws + off); off += (size_t)BB * 210 * 128 * 2;
    unsigned short* xpT4 = (unsigned short*)(ws + off); off += (size_t)BB * 200 * 64 * 2;
    unsigned short* wT1  = (unsigned short*)(ws + off); off += (size_t)5 * 256 * 160 * 2;
    unsigned short* wT2  = (unsigned short*)(ws + off); off += (size_t)3 * 128 * 256 * 2;
    unsigned short* wT3  = (unsigned short*)(ws + off); off += (size_t)3 * 64 * 128 * 2;
    float* control   = (float*)(ws + off);
    float* avg_shape = control + 102400;
    float* loc_w     = avg_shape + 2048;
    float* acc       = loc_w + 320;
    float* z0        = acc + 64;
    float* scale     = z0 + 64;
    float* fbins     = scale + 64;

    dim3 blk(256);

    init_kernel<<<1, 64, 0, stream>>>(acc, z0);

    // prep
    {
        int n1 = BB * 212 * 160;
        prep_x1_kernel<<<dim3((n1 + 255) / 256), blk, 0, stream>>>(cond, f0, xpT1);
        int z2 = (BB * 210 * 256 * 2) / 16;
        zero16_kernel<<<dim3((z2 + 255) / 256), blk, 0, stream>>>((uint4*)xpT2, z2);
        int z3 = (BB * 210 * 128 * 2) / 16;
        zero16_kernel<<<dim3((z3 + 255) / 256), blk, 0, stream>>>((uint4*)xpT3, z3);
        prep_w_kernel<5, 129, 160, 256><<<dim3((5 * 256 * 160 + 255) / 256), blk, 0, stream>>>(w1, wT1);
        prep_w_kernel<3, 256, 256, 128><<<dim3((3 * 128 * 256 + 255) / 256), blk, 0, stream>>>(w2, wT2);
        prep_w_kernel<3, 128, 128, 64><<<dim3((3 * 64 * 128 + 255) / 256), blk, 0, stream>>>(w3, wT3);
    }

    // MFMA conv stack
    conv_mfma_kernel<4, 5, 5, 160, 256><<<dim3(13, BB), blk, 0, stream>>>(
        xpT1, 212, wT1, b1, xpT2, 210, 1);
    conv_mfma_kernel<2, 3, 8, 256, 128><<<dim3(13, BB), blk, 0, stream>>>(
        xpT2, 210, wT2, b2, xpT3, 210, 1);
    conv_mfma_kernel<1, 3, 4, 128, 64><<<dim3(13, BB), blk, 0, stream>>>(
        xpT3, 210, wT3, b3, xpT4, 200, 0);

    head_kernel<<<dim3(BB), blk, 0, stream>>>(xpT4, w4, b4, control, avg_shape, bf_out);
    locw_mean_kernel<<<dim3(5, BB), blk, 0, stream>>>(control, loc_w);
    fbins_kernel<<<dim3((NBINS + 255) / 256), blk, 0, stream>>>(fbins);

    // batch-paired four-step FFT pipeline (32 complex signals carry 64 real batches)
    passA_kernel<<<dim3(50, 32), blk, 0, stream>>>(wn, I);
    passBp_kernel<0><<<dim3(40, 32), blk, 0, stream>>>(I, avg_shape, fbins, loc_w, acc, z0);
    finalize_scale<<<1, 64, 0, stream>>>(acc, z0, scale);
    passC_kernel<<<dim3(50, 32), blk, 0, stream>>>(I, control, f0, scale);
    passBp_kernel<1><<<dim3(40, 32), blk, 0, stream>>>(I, avg_shape, fbins, loc_w, acc, z0);
    passD_kernel<<<dim3(50, 32), blk, 0, stream>>>(I, filtered);
}

// Round 11
// 378.903 us; speedup vs baseline: 1.5445x; 1.0689x over previous
//
#include <hip/hip_runtime.h>
#include <math.h>

#define BB 64
#define T_FR 200
#define NA 48000
#define NBINS 24001

typedef __attribute__((ext_vector_type(4))) float f32x4;
typedef __attribute__((ext_vector_type(8))) short bf16x8;

__device__ __forceinline__ unsigned short f2bf(float x)
{
    unsigned u = __float_as_uint(x);
    u = (u + 0x7FFFu + ((u >> 16) & 1u)) >> 16;
    return (unsigned short)u;
}
__device__ __forceinline__ float bf2f(unsigned short h)
{
    return __uint_as_float(((unsigned)h) << 16);
}

__device__ inline float2 cmul(float2 a, float2 b)
{
    return make_float2(a.x * b.x - a.y * b.y, a.x * b.y + a.y * b.x);
}

__device__ __forceinline__ float2 cis_rev(float rev)
{
    return make_float2(__builtin_amdgcn_cosf(rev), __builtin_amdgcn_sinf(rev));
}

// ---------------- root tables ----------------
template<int R> __device__ __forceinline__ void fill_roots(float (&cr)[R], float (&si)[R]);
template<> __device__ __forceinline__ void fill_roots<3>(float (&cr)[3], float (&si)[3])
{
    const float S = 0.86602540378443865f;
    cr[0]=1.f; cr[1]=-0.5f; cr[2]=-0.5f;
    si[0]=0.f; si[1]=S;     si[2]=-S;
}
template<> __device__ __forceinline__ void fill_roots<4>(float (&cr)[4], float (&si)[4])
{
    cr[0]=1.f; cr[1]=0.f; cr[2]=-1.f; cr[3]=0.f;
    si[0]=0.f; si[1]=1.f; si[2]=0.f;  si[3]=-1.f;
}
template<> __device__ __forceinline__ void fill_roots<5>(float (&cr)[5], float (&si)[5])
{
    cr[0]=1.f; cr[1]=0.30901699437494742f; cr[2]=-0.80901699437494742f;
    cr[3]=-0.80901699437494742f; cr[4]=0.30901699437494742f;
    si[0]=0.f; si[1]=0.95105651629515357f; si[2]=0.58778525229247313f;
    si[3]=-0.58778525229247313f; si[4]=-0.95105651629515357f;
}
template<> __device__ __forceinline__ void fill_roots<8>(float (&cr)[8], float (&si)[8])
{
    const float C = 0.70710678118654752f;
    cr[0]=1.f; cr[1]=C;  cr[2]=0.f;  cr[3]=-C; cr[4]=-1.f; cr[5]=-C;  cr[6]=0.f;  cr[7]=C;
    si[0]=0.f; si[1]=C;  si[2]=1.f;  si[3]=C;  si[4]=0.f;  si[5]=-C;  si[6]=-1.f; si[7]=-C;
}

template<int S, int R>
__device__ __forceinline__ void dftR(float2 (&v)[R])
{
    float cr[R], si[R];
    fill_roots<R>(cr, si);
    float2 o[R];
#pragma unroll
    for (int k = 0; k < R; ++k) {
        float re = 0.f, im = 0.f;
#pragma unroll
        for (int j = 0; j < R; ++j) {
            int m = (j * k) % R;
            float ur = cr[m], ui = (S > 0) ? si[m] : -si[m];
            re += v[j].x * ur - v[j].y * ui;
            im += v[j].x * ui + v[j].y * ur;
        }
        o[k] = make_float2(re, im);
    }
#pragma unroll
    for (int k = 0; k < R; ++k) v[k] = o[k];
}

__device__ __constant__ float C25R[17] = {1.f,0.968583161f,0.876306680f,0.728968627f,0.535826795f,0.309016994f,0.062790520f,-0.187381315f,-0.425779292f,-0.637423990f,-0.809016994f,-0.929776486f,-0.992114701f,-0.992114701f,-0.929776486f,-0.809016994f,-0.637423990f};
__device__ __constant__ float C25I[17] = {0.f,0.248689887f,0.481753674f,0.684547106f,0.844327926f,0.951056516f,0.998026728f,0.982287251f,0.904827052f,0.770513243f,0.587785252f,0.368124553f,0.125333234f,-0.125333234f,-0.368124553f,-0.587785252f,-0.770513243f};
__device__ __constant__ float C15R[9] = {1.f,0.913545458f,0.669130606f,0.309016994f,-0.104528463f,-0.5f,-0.809016994f,-0.978147601f,-0.978147601f};
__device__ __constant__ float C15I[9] = {0.f,0.406736643f,0.743144825f,0.951056516f,0.994521895f,0.866025404f,0.587785252f,0.207911691f,-0.207911691f};
__device__ __constant__ float C16R[10] = {1.f,0.923879533f,0.707106781f,0.382683432f,0.f,-0.382683432f,-0.707106781f,-0.923879533f,-1.f,-0.923879533f};
__device__ __constant__ float C16I[10] = {0.f,0.382683432f,0.707106781f,0.923879533f,1.f,0.923879533f,0.707106781f,0.382683432f,0.f,-0.382683432f};

template<int S> __device__ __forceinline__ float2 tw25(int m){ return make_float2(C25R[m], S>0? C25I[m] : -C25I[m]); }
template<int S> __device__ __forceinline__ float2 tw15(int m){ return make_float2(C15R[m], S>0? C15I[m] : -C15I[m]); }
template<int S> __device__ __forceinline__ float2 tw16(int m){ return make_float2(C16R[m], S>0? C16I[m] : -C16I[m]); }

// ======== in-place micro-stages (read-set == write-set per item) ========
// --- 200 = 8 x (5 x 5) ---
template<int SGN> __device__ __forceinline__ void s200_1(float2* row, int g)
{
    float2 v[8];
#pragma unroll
    for (int j = 0; j < 8; ++j) v[j] = row[25 * j + g];
    float gs = (float)(SGN * g) * (1.f / 200.f);
    if (SGN < 0) {
        dftR<-1, 8>(v);
#pragma unroll
        for (int k = 1; k < 8; ++k) v[k] = cmul(v[k], cis_rev(gs * (float)k));
    } else {
#pragma unroll
        for (int k = 1; k < 8; ++k) v[k] = cmul(v[k], cis_rev(gs * (float)k));
        dftR<+1, 8>(v);
    }
#pragma unroll
    for (int j = 0; j < 8; ++j) row[25 * j + g] = v[j];
}
template<int SGN> __device__ __forceinline__ void s200_2a(float2* row, int k1, int bq)
{
    float2 u[5];
    int base = 25 * k1 + bq;
#pragma unroll
    for (int a = 0; a < 5; ++a) u[a] = row[base + 5 * a];
    if (SGN < 0) {
        dftR<-1, 5>(u);
#pragma unroll
        for (int c = 1; c < 5; ++c) if (bq) u[c] = cmul(u[c], tw25<-1>(c * bq));
    } else {
#pragma unroll
        for (int c = 1; c < 5; ++c) if (bq) u[c] = cmul(u[c], tw25<+1>(c * bq));
        dftR<+1, 5>(u);
    }
#pragma unroll
    for (int c = 0; c < 5; ++c) row[base + 5 * c] = u[c];
}
template<int SGN> __device__ __forceinline__ void s200_3(float2* row, int base)
{
    float2 u[5];
#pragma unroll
    for (int i = 0; i < 5; ++i) u[i] = row[base + i];
    dftR<SGN, 5>(u);
#pragma unroll
    for (int i = 0; i < 5; ++i) row[base + i] = u[i];
}
// full-spectrum slot for k2: slot = 25*(k2%8) + 5*((k2/8)%5) + (k2/40)
__device__ __forceinline__ int slot200(int k2)
{
    int A = k2 & 7;
    int r = k2 >> 3;
    return 25 * A + 5 * (r % 5) + (r / 5);
}

// --- 240 = (4x4) x (5x3) ---
template<int SGN> __device__ __forceinline__ void s240_1a(float2* col, int g, int bq)
{
    float2 u[4];
#pragma unroll
    for (int a = 0; a < 4; ++a) u[a] = col[15 * (4 * a + bq) + g];
    if (SGN < 0) {
        dftR<-1, 4>(u);
#pragma unroll
        for (int c = 1; c < 4; ++c) if (bq) u[c] = cmul(u[c], tw16<-1>(c * bq));
    } else {
#pragma unroll
        for (int c = 1; c < 4; ++c) if (bq) u[c] = cmul(u[c], tw16<+1>(c * bq));
        dftR<+1, 4>(u);
    }
#pragma unroll
    for (int c = 0; c < 4; ++c) col[15 * (4 * c + bq) + g] = u[c];
}
template<int SGN> __device__ __forceinline__ void s240_1b(float2* col, int g, int c)
{
    float2 u[4];
    float gs = (float)(SGN * g) * (1.f / 240.f);
#pragma unroll
    for (int i = 0; i < 4; ++i) u[i] = col[15 * (4 * c + i) + g];
    if (SGN < 0) {
        dftR<-1, 4>(u);
#pragma unroll
        for (int d = 0; d < 4; ++d) { int k1 = c + 4 * d; if (k1) u[d] = cmul(u[d], cis_rev(gs * (float)k1)); }
    } else {
#pragma unroll
        for (int d = 0; d < 4; ++d) { int k1 = c + 4 * d; if (k1) u[d] = cmul(u[d], cis_rev(gs * (float)k1)); }
        dftR<+1, 4>(u);
    }
#pragma unroll
    for (int i = 0; i < 4; ++i) col[15 * (4 * c + i) + g] = u[i];
}
template<int SGN> __device__ __forceinline__ void s240_2a(float2* col, int p, int bq)
{
    float2 u[5];
    int base = 15 * p + bq;
#pragma unroll
    for (int a = 0; a < 5; ++a) u[a] = col[base + 3 * a];
    if (SGN < 0) {
        dftR<-1, 5>(u);
#pragma unroll
        for (int c = 1; c < 5; ++c) if (bq) u[c] = cmul(u[c], tw15<-1>(c * bq));
    } else {
#pragma unroll
        for (int c = 1; c < 5; ++c) if (bq) u[c] = cmul(u[c], tw15<+1>(c * bq));
        dftR<+1, 5>(u);
    }
#pragma unroll
    for (int c = 0; c < 5; ++c) col[base + 3 * c] = u[c];
}
__device__ __forceinline__ int p2k1(int p) { return ((p & 3) << 2) | (p >> 2); }

// Hermitian pair combine (verified round 10)
__device__ __forceinline__ void pair_combine(float2 Za, float2 Zb, float g1, float g2,
                                             float2& C, float2& Cp, float& e1, float& e2)
{
    float2 X1 = make_float2(0.5f * (Za.x + Zb.x), 0.5f * (Za.y - Zb.y));
    float2 w  = make_float2(0.5f * (Za.x - Zb.x), 0.5f * (Za.y + Zb.y));
    float2 X2 = make_float2(w.y, -w.x);
    float2 Z1 = make_float2(g1 * X1.x, g1 * X1.y);
    float2 Z2 = make_float2(g2 * X2.x, g2 * X2.y);
    e1 = Z1.x * Z1.x + Z1.y * Z1.y;
    e2 = Z2.x * Z2.x + Z2.y * Z2.y;
    C  = make_float2(Z1.x - Z2.y,  Z1.y + Z2.x);
    Cp = make_float2(Z1.x + Z2.y, -Z1.y + Z2.x);
}

// ================= MFMA conv (unchanged, verified) =================
template<int NT, int TAPS, int CHUNKS, int CINP, int COUTP>
__global__ __launch_bounds__(256) void conv_mfma_kernel(
    const unsigned short* __restrict__ xT, int tRowsIn,
    const unsigned short* __restrict__ wT,
    const float* __restrict__ bias,
    unsigned short* __restrict__ outT, int tRowsOut, int tOffOut)
{
    const int b = blockIdx.y;
    const int t0 = blockIdx.x * 16;
    const int tid = threadIdx.x;
    const int wave = tid >> 6;
    const int lane = tid & 63;
    const int m = lane & 15;
    const int quad = lane >> 4;
    const int n0 = wave * (NT * 16);

    f32x4 acc[NT];
#pragma unroll
    for (int nt = 0; nt < NT; ++nt) acc[nt] = (f32x4){0.f, 0.f, 0.f, 0.f};

    const unsigned short* xb = xT + (size_t)b * tRowsIn * CINP;
#pragma unroll
    for (int kw = 0; kw < TAPS; ++kw) {
        const unsigned short* wk = wT + (size_t)kw * COUTP * CINP;
        const unsigned short* xrow = xb + (size_t)(t0 + kw + m) * CINP + quad * 8;
#pragma unroll
        for (int ch = 0; ch < CHUNKS; ++ch) {
            const int k0 = ch * 32;
            bf16x8 a = *(const bf16x8*)(xrow + k0);
#pragma unroll
            for (int nt = 0; nt < NT; ++nt) {
                bf16x8 bfr = *(const bf16x8*)(wk + (size_t)(n0 + nt * 16 + m) * CINP + k0 + quad * 8);
                acc[nt] = __builtin_amdgcn_mfma_f32_16x16x32_bf16(a, bfr, acc[nt], 0, 0, 0);
            }
        }
    }
#pragma unroll
    for (int nt = 0; nt < NT; ++nt) {
        const int n = n0 + nt * 16 + m;
        const float bz = bias[n];
#pragma unroll
        for (int r = 0; r < 4; ++r) {
            const int t = t0 + quad * 4 + r;
            if (t < 200) {
                float v = acc[nt][r] + bz;
                v = (v >= 0.f) ? v : 0.1f * v;
                outT[((size_t)b * tRowsOut + t + tOffOut) * COUTP + n] = f2bf(v);
            }
        }
    }
}

__global__ void prep_x1_kernel(const float* __restrict__ cond, const float* __restrict__ f0,
                               unsigned short* __restrict__ xpT1)
{
    int idx = blockIdx.x * 256 + threadIdx.x;
    const int total = BB * 212 * 160;
    if (idx >= total) return;
    int i = idx % 160;
    int rest = idx / 160;
    int tp = rest % 212;
    int b = rest / 212;
    int tt = tp - 2;
    float v = 0.f;
    if (tt >= 0 && tt < 200) {
        if (i < 128) v = cond[((size_t)b * 128 + i) * 200 + tt];
        else if (i == 128) v = (f0[b * 200 + tt] > 0.f) ? 1.f : 0.f;
    }
    xpT1[idx] = f2bf(v);
}

template<int TAPS, int CINR, int CINP, int COUTP>
__global__ void prep_w_kernel(const float* __restrict__ w, unsigned short* __restrict__ wT)
{
    int idx = blockIdx.x * 256 + threadIdx.x;
    const int total = TAPS * COUTP * CINP;
    if (idx >= total) return;
    int i = idx % CINP;
    int rest = idx / CINP;
    int o = rest % COUTP;
    int kw = rest / COUTP;
    float v = (i < CINR) ? w[((size_t)o * CINR + i) * TAPS + kw] : 0.f;
    wT[idx] = f2bf(v);
}

__global__ void zero16_kernel(uint4* __restrict__ p, int n16)
{
    int idx = blockIdx.x * 256 + threadIdx.x;
    if (idx < n16) p[idx] = make_uint4(0, 0, 0, 0);
}

// ================= FFT passes (batch-paired, restored 8-col / 12-row tiles) =================

// pass A: z = wn[2q] + i wn[2q+1] -> I[q][kg][n2]  (8 columns/block, 25x32 grid)
__global__ __launch_bounds__(256) void passA_kernel(const float* __restrict__ wn,
                                                    float2* __restrict__ I)
{
    __shared__ float2 L[8 * 241];
    int q = blockIdx.y;
    const float* w1p = wn + (size_t)(2 * q) * NA;
    const float* w2p = wn + (size_t)(2 * q + 1) * NA;
    int n20 = blockIdx.x * 8;
    int tid = threadIdx.x;
    for (int idx = tid; idx < 1920; idx += 256) {
        int n1 = idx >> 3, j = idx & 7;
        int n = n1 * 200 + n20 + j;
        L[j * 241 + n1] = make_float2(w1p[n], w2p[n]);
    }
    __syncthreads();
    for (int idx = tid; idx < 480; idx += 256) {
        int j = idx & 7, r = idx >> 3;
        s240_1a<-1>(L + j * 241, r >> 2, r & 3);
    }
    __syncthreads();
    for (int idx = tid; idx < 480; idx += 256) {
        int j = idx & 7, r = idx >> 3;
        s240_1b<-1>(L + j * 241, r >> 2, r & 3);
    }
    __syncthreads();
    for (int idx = tid; idx < 384; idx += 256) {
        int j = idx & 7, r = idx >> 3;
        s240_2a<-1>(L + j * 241, r / 3, r - 3 * (r / 3));
    }
    __syncthreads();
    for (int idx = tid; idx < 640; idx += 256) {
        int j = idx & 7, r = idx >> 3;
        int p = r / 5, c = r - 5 * p;
        float2* col = L + j * 241;
        float2 u[3];
#pragma unroll
        for (int i = 0; i < 3; ++i) u[i] = col[15 * p + 3 * c + i];
        dftR<-1, 3>(u);
        int k1 = p2k1(p);
        int n2 = n20 + j;
#pragma unroll
        for (int d = 0; d < 3; ++d) {
            int kg = k1 + 16 * (c + 5 * d);
            float2 tw = cis_rev(-(float)(n2 * kg) * (1.f / (float)NA));
            I[(size_t)q * NA + kg * 200 + n2] = cmul(u[d], tw);
        }
    }
}

// pass B (paired): 6 conjugate row-pairs (12 rows) per block (20x32 grid).
template<int MODE>
__global__ __launch_bounds__(256) void passBp_kernel(float2* __restrict__ I,
    const float* __restrict__ avg_shape, const float* __restrict__ fbins,
    const float* __restrict__ loc_w, float* __restrict__ acc, float* __restrict__ z0)
{
    __shared__ float2 L[12 * 202];
    __shared__ float g1sh[32], g2sh[32];
    int q = blockIdx.y;
    int b1 = 2 * q, b2 = 2 * q + 1;
    int bx = blockIdx.x;
    int tid = threadIdx.x;
    if (MODE == 0) {
        if (tid < 32) { g1sh[tid] = avg_shape[b1 * 32 + tid]; g2sh[tid] = avg_shape[b2 * 32 + tid]; }
    } else {
        if (tid < 5) { g1sh[tid] = loc_w[b1 * 5 + tid]; g2sh[tid] = loc_w[b2 * 5 + tid]; }
    }
    int Rrow[12];
#pragma unroll
    for (int s = 0; s < 12; ++s) {
        int p = s >> 1;
        int pi = 6 * bx + p;
        Rrow[s] = (pi == 0) ? ((s & 1) ? 120 : 0) : ((s & 1) ? 240 - pi : pi);
    }
    for (int idx = tid; idx < 2400; idx += 256) {
        int s = idx / 200, e = idx - s * 200;
        L[s * 202 + e] = I[(size_t)q * NA + Rrow[s] * 200 + e];
    }
    __syncthreads();
    for (int idx = tid; idx < 300; idx += 256) {
        int s = idx / 25, g = idx - s * 25;
        s200_1<-1>(L + s * 202, g);
    }
    __syncthreads();
    for (int idx = tid; idx < 480; idx += 256) {
        int s = idx / 40, r = idx - s * 40;
        s200_2a<-1>(L + s * 202, r / 5, r - 5 * (r / 5));
    }
    __syncthreads();
    for (int idx = tid; idx < 480; idx += 256) {
        int s = idx / 40, r = idx - s * 40;
        s200_3<-1>(L + s * 202, 25 * (r / 5) + 5 * (r - 5 * (r / 5)));
    }
    __syncthreads();
    float part1 = 0.f, part2 = 0.f;
    for (int idx = tid; idx < 1206; idx += 256) {
        int p = idx / 201, t = idx - p * 201;
        int pi = 6 * bx + p;
        float2* rwA = L + (2 * p) * 202;
        float2* rwB = L + (2 * p + 1) * 202;
        int k = -1;
        float2 Za, Zb;
        int sa = 0, sb = 0;
        float2* wa = rwA; float2* wb = rwB;
        bool self1 = false;
        if (pi != 0) {
            if (t >= 200) continue;
            int k2 = t, k2p = 199 - t;
            sa = slot200(k2); sb = slot200(k2p);
            Za = rwA[sa]; Zb = rwB[sb];
            k = pi + 240 * k2;
        } else if (t < 101) {
            wa = rwA; wb = rwA;
            if (t == 0 || t == 100) {
                sa = slot200(t); sb = sa;
                Za = rwA[sa]; Zb = Za;
                k = 240 * t;
                self1 = true;
            } else {
                sa = slot200(t); sb = slot200(200 - t);
                Za = rwA[sa]; Zb = rwA[sb];
                k = 240 * t;
            }
        } else {
            int t2 = t - 101;
            if (t2 >= 100) continue;
            wa = rwB; wb = rwB;
            sa = slot200(t2); sb = slot200(199 - t2);
            Za = rwB[sa]; Zb = rwB[sb];
            k = 120 + 240 * t2;
        }
        int kbin = min(k, NA - k);
        float g1, g2;
        if (MODE == 0) {
            int jj = (kbin * 32) / NBINS;
            if (jj < 31 && (NBINS * (jj + 1)) / 32 <= kbin) ++jj;
            g1 = g1sh[jj]; g2 = g2sh[jj];
        } else {
            g1 = 0.f; g2 = 0.f;
#pragma unroll
            for (int c = 0; c < 5; ++c) {
                float fb = fbins[c * NBINS + kbin];
                g1 += g1sh[c] * fb; g2 += g2sh[c] * fb;
            }
        }
        float2 C, Cp; float e1, e2;
        pair_combine(Za, Zb, g1, g2, C, Cp, e1, e2);
        if (MODE == 0) {
            float wgt = self1 ? 1.f : 2.f;
            part1 += wgt * e1; part2 += wgt * e2;
            if (k == 0) { z0[b1] = g1 * Za.x; z0[b2] = g2 * Za.y; }
        }
        wa[sa] = make_float2(C.x * (1.f / NA), C.y * (1.f / NA));
        if (!self1) wb[sb] = make_float2(Cp.x * (1.f / NA), Cp.y * (1.f / NA));
    }
    if (MODE == 0) {
        for (int o = 32; o > 0; o >>= 1) {
            part1 += __shfl_down(part1, o);
            part2 += __shfl_down(part2, o);
        }
        if ((tid & 63) == 0) { atomicAdd(&acc[b1], part1); atomicAdd(&acc[b2], part2); }
    }
    __syncthreads();
    for (int idx = tid; idx < 480; idx += 256) {
        int s = idx / 40, r = idx - s * 40;
        s200_3<+1>(L + s * 202, 25 * (r / 5) + 5 * (r - 5 * (r / 5)));
    }
    __syncthreads();
    for (int idx = tid; idx < 480; idx += 256) {
        int s = idx / 40, r = idx - s * 40;
        s200_2a<+1>(L + s * 202, r / 5, r - 5 * (r / 5));
    }
    __syncthreads();
    for (int idx = tid; idx < 300; idx += 256) {
        int s = idx / 25, g = idx - s * 25;
        s200_1<+1>(L + s * 202, g);
    }
    __syncthreads();
    for (int idx = tid; idx < 2400; idx += 256) {
        int s = idx / 200, n2 = idx - s * 200;
        int k1g = Rrow[s];
        float2 tw = cis_rev((float)(n2 * k1g) * (1.f / (float)NA));
        I[(size_t)q * NA + k1g * 200 + n2] = cmul(L[s * 202 + n2], tw);
    }
}

// pass C: inv240 -> per-batch scale*mod -> fwd240 (8 columns/block, 25x32)
__global__ __launch_bounds__(256) void passC_kernel(float2* __restrict__ I,
    const float* __restrict__ control, const float* __restrict__ f0,
    const float* __restrict__ scale)
{
    __shared__ float2 L[8 * 241];
    __shared__ float ctlA[600], ctlB[600];
    __shared__ float f0A[200], f0B[200];
    int q = blockIdx.y;
    int b1 = 2 * q, b2 = 2 * q + 1;
    int n20 = blockIdx.x * 8;
    int tid = threadIdx.x;
    for (int i = tid; i < 600; i += 256) {
        ctlA[i] = control[(size_t)b1 * 1600 + i];
        ctlB[i] = control[(size_t)b2 * 1600 + i];
    }
    for (int i = tid; i < 200; i += 256) {
        f0A[i] = f0[b1 * 200 + i];
        f0B[i] = f0[b2 * 200 + i];
    }
    for (int idx = tid; idx < 640; idx += 256) {
        int j = idx & 7, r = idx >> 3;
        int p = r / 5, c = r - 5 * p;
        int k1 = p2k1(p);
        int n2 = n20 + j;
        float2 u[3];
#pragma unroll
        for (int d = 0; d < 3; ++d) {
            int kg = k1 + 16 * (c + 5 * d);
            u[d] = I[(size_t)q * NA + kg * 200 + n2];
        }
        dftR<+1, 3>(u);
        float2* col = L + j * 241;
#pragma unroll
        for (int i = 0; i < 3; ++i) col[15 * p + 3 * c + i] = u[i];
    }
    __syncthreads();
    for (int idx = tid; idx < 384; idx += 256) {
        int j = idx & 7, r = idx >> 3;
        s240_2a<+1>(L + j * 241, r / 3, r - 3 * (r / 3));
    }
    __syncthreads();
    for (int idx = tid; idx < 480; idx += 256) {
        int j = idx & 7, r = idx >> 3;
        s240_1b<+1>(L + j * 241, r >> 2, r & 3);
    }
    __syncthreads();
    for (int idx = tid; idx < 480; idx += 256) {
        int j = idx & 7, r = idx >> 3;
        s240_1a<+1>(L + j * 241, r >> 2, r & 3);
    }
    __syncthreads();
    float sc1 = scale[b1], sc2 = scale[b2];
    for (int idx = tid; idx < 1920; idx += 256) {
        int n1 = idx >> 3, j = idx & 7;
        int n2 = n20 + j;
        int n = 200 * n1 + n2;
        float sf = ((float)n + 0.5f) * (1.f / 240.f) - 0.5f;
        sf = fminf(fmaxf(sf, 0.f), 199.f);
        int i0 = (int)sf;
        int i1 = min(i0 + 1, 199);
        float w = sf - (float)i0;
        float w0 = 1.f - w;
        float inh = ctlA[i0] * w0 + ctlA[i1] * w;
        float exh = ctlA[200 + i0] * w0 + ctlA[200 + i1] * w;
        float pr  = ctlA[400 + i0] * w0 + ctlA[400 + i1] * w;
        float vv  = (f0A[i0] > 0.f ? 1.f : 0.f) * w0 + (f0A[i1] > 0.f ? 1.f : 0.f) * w;
        float m1 = inh * (1.f - vv) + exh * pr;
        inh = ctlB[i0] * w0 + ctlB[i1] * w;
        exh = ctlB[200 + i0] * w0 + ctlB[200 + i1] * w;
        pr  = ctlB[400 + i0] * w0 + ctlB[400 + i1] * w;
        vv  = (f0B[i0] > 0.f ? 1.f : 0.f) * w0 + (f0B[i1] > 0.f ? 1.f : 0.f) * w;
        float m2 = inh * (1.f - vv) + exh * pr;
        float2 z = L[j * 241 + n1];
        L[j * 241 + n1] = make_float2(z.x * sc1 * m1, z.y * sc2 * m2);
    }
    __syncthreads();
    for (int idx = tid; idx < 480; idx += 256) {
        int j = idx & 7, r = idx >> 3;
        s240_1a<-1>(L + j * 241, r >> 2, r & 3);
    }
    __syncthreads();
    for (int idx = tid; idx < 480; idx += 256) {
        int j = idx & 7, r = idx >> 3;
        s240_1b<-1>(L + j * 241, r >> 2, r & 3);
    }
    __syncthreads();
    for (int idx = tid; idx < 384; idx += 256) {
        int j = idx & 7, r = idx >> 3;
        s240_2a<-1>(L + j * 241, r / 3, r - 3 * (r / 3));
    }
    __syncthreads();
    for (int idx = tid; idx < 640; idx += 256) {
        int j = idx & 7, r = idx >> 3;
        int p = r / 5, c = r - 5 * p;
        float2* col = L + j * 241;
        float2 u[3];
#pragma unroll
        for (int i = 0; i < 3; ++i) u[i] = col[15 * p + 3 * c + i];
        dftR<-1, 3>(u);
        int k1 = p2k1(p);
        int n2 = n20 + j;
#pragma unroll
        for (int d = 0; d < 3; ++d) {
            int kg = k1 + 16 * (c + 5 * d);
            float2 tw = cis_rev(-(float)(n2 * kg) * (1.f / (float)NA));
            I[(size_t)q * NA + kg * 200 + n2] = cmul(u[d], tw);
        }
    }
}

// pass D: inv240 -> two real outputs (8 columns/block, 25x32)
__global__ __launch_bounds__(256) void passD_kernel(const float2* __restrict__ I,
                                                    float* __restrict__ out)
{
    __shared__ float2 L[8 * 241];
    int q = blockIdx.y;
    int b1 = 2 * q, b2 = 2 * q + 1;
    int n20 = blockIdx.x * 8;
    int tid = threadIdx.x;
    for (int idx = tid; idx < 640; idx += 256) {
        int j = idx & 7, r = idx >> 3;
        int p = r / 5, c = r - 5 * p;
        int k1 = p2k1(p);
        int n2 = n20 + j;
        float2 u[3];
#pragma unroll
        for (int d = 0; d < 3; ++d) {
            int kg = k1 + 16 * (c + 5 * d);
            u[d] = I[(size_t)q * NA + kg * 200 + n2];
        }
        dftR<+1, 3>(u);
        float2* col = L + j * 241;
#pragma unroll
        for (int i = 0; i < 3; ++i) col[15 * p + 3 * c + i] = u[i];
    }
    __syncthreads();
    for (int idx = tid; idx < 384; idx += 256) {
        int j = idx & 7, r = idx >> 3;
        s240_2a<+1>(L + j * 241, r / 3, r - 3 * (r / 3));
    }
    __syncthreads();
    for (int idx = tid; idx < 480; idx += 256) {
        int j = idx & 7, r = idx >> 3;
        s240_1b<+1>(L + j * 241, r >> 2, r & 3);
    }
    __syncthreads();
    for (int idx = tid; idx < 480; idx += 256) {
        int j = idx & 7, r = idx >> 3;
        s240_1a<+1>(L + j * 241, r >> 2, r & 3);
    }
    __syncthreads();
    for (int idx = tid; idx < 1920; idx += 256) {
        int n1 = idx >> 3, j = idx & 7;
        int n = 200 * n1 + n20 + j;
        float2 z = L[j * 241 + n1];
        out[(size_t)b1 * NA + n] = z.x;
        out[(size_t)b2 * NA + n] = z.y;
    }
}

__global__ void init_kernel(float* __restrict__ acc, float* __restrict__ z0)
{
    int i = threadIdx.x;
    if (i < 64) { acc[i] = 0.f; z0[i] = 0.f; }
}

__global__ void finalize_scale(const float* __restrict__ acc, const float* __restrict__ z0,
                               float* __restrict__ scale)
{
    int b = threadIdx.x;
    if (b < 64) {
        float var = (acc[b] - z0[b] * z0[b]) / (48000.f * 47999.f);
        scale[b] = 0.1f / sqrtf(var);
    }
}

// ---------------- head ----------------
__global__ void head_kernel(const unsigned short* __restrict__ h3T, const float* __restrict__ w4,
                            const float* __restrict__ b4, float* __restrict__ control,
                            float* __restrict__ avg_shape, float* __restrict__ out_bf)
{
    __shared__ float w4s[40 * 64];
    __shared__ float b4s[40];
    __shared__ float sp[200 * 33];
    int b = blockIdx.x;
    for (int j = threadIdx.x; j < 40 * 64; j += 256) w4s[j] = w4[j];
    if (threadIdx.x < 40) b4s[threadIdx.x] = b4[threadIdx.x];
    __syncthreads();
    int t = threadIdx.x;
    if (t < 200) {
        float p[40];
#pragma unroll
        for (int o = 0; o < 40; ++o) p[o] = b4s[o];
        const unsigned short* hb = h3T + ((size_t)b * 200 + t) * 64;
        for (int i = 0; i < 64; ++i) {
            float h = bf2f(hb[i]);
#pragma unroll
            for (int o = 0; o < 40; ++o) p[o] += h * w4s[o * 64 + i];
        }
        float inh = 1.f / (1.f + expf(-p[0]));
        float exh = 1.f / (1.f + expf(-p[1]));
        float pr  = 1.f / (1.f + expf(-p[2]));
        float mx = p[3];
#pragma unroll
        for (int c = 1; c < 32; ++c) mx = fmaxf(mx, p[3 + c]);
        float e[32];
        float sum = 0.f;
#pragma unroll
        for (int c = 0; c < 32; ++c) { e[c] = expf(p[3 + c] - mx); sum += e[c]; }
        float inv = 1.f / sum;
#pragma unroll
        for (int c = 0; c < 32; ++c) sp[t * 33 + c] = e[c] * inv;
        float mx2 = p[35];
#pragma unroll
        for (int c = 1; c < 5; ++c) mx2 = fmaxf(mx2, p[35 + c]);
        float e2[5];
        float s2 = 0.f;
#pragma unroll
        for (int c = 0; c < 5; ++c) { e2[c] = expf(p[35 + c] - mx2); s2 += e2[c]; }
        float inv2 = 1.f / s2;
        float* ctl = control + (size_t)b * 8 * 200;
        ctl[0 * 200 + t] = inh;
        ctl[1 * 200 + t] = exh;
        ctl[2 * 200 + t] = pr;
#pragma unroll
        for (int c = 0; c < 5; ++c) ctl[(3 + c) * 200 + t] = e2[c] * inv2;
        float* bf = out_bf + (size_t)b * 3 * 200;
        bf[0 * 200 + t] = pr;
        bf[1 * 200 + t] = inh;
        bf[2 * 200 + t] = exh;
    }
    __syncthreads();
    if (t < 32) {
        float s = 0.f;
        for (int j = 0; j < 200; ++j) s += sp[j * 33 + t];
        avg_shape[b * 32 + t] = s * (1.f / 200.f);
    }
}

// loc_w[b,c] = mean_t turb[b,c,t] (interp weights analytically uniform = 1/200)
__global__ void locw_mean_kernel(const float* __restrict__ control, float* __restrict__ loc_w)
{
    int c = blockIdx.x, b = blockIdx.y;
    int tid = threadIdx.x;
    const float* src = control + ((size_t)b * 8 + 3 + c) * 200;
    float s = (tid < 200) ? src[tid] : 0.f;
    for (int o = 32; o > 0; o >>= 1) s += __shfl_down(s, o);
    __shared__ float red[4];
    if ((tid & 63) == 0) red[tid >> 6] = s;
    __syncthreads();
    if (tid == 0) loc_w[b * 5 + c] = (red[0] + red[1] + red[2] + red[3]) * (1.f / 200.f);
}

__device__ inline float filter_shape_val(int c, int i)
{
    float lin = (float)i * (1.f / 31.f);
    if (c == 0) { float z = (lin - 0.2f) * 10.f;          return expf(-0.5f * z * z); }
    if (c == 1) { float z = (lin - 0.1f) * 10.f;          return expf(-0.5f * z * z); }
    if (c == 2) { float z = (lin - 0.4f) * (1.f / 0.15f); return expf(-0.5f * z * z); }
    if (c == 3) { float z = (lin - 0.6f) * 10.f;          return expf(-0.5f * z * z); }
    float v = 0.1f + 0.9f * lin;
    return v * v;
}

__global__ void fbins_kernel(float* __restrict__ fbins)
{
    int k = blockIdx.x * 256 + threadIdx.x;
    if (k >= NBINS) return;
    float sf = (k + 0.5f) * (32.0f / 24001.0f) - 0.5f;
    sf = fminf(fmaxf(sf, 0.f), 31.f);
    int i0 = (int)sf;
    int i1 = min(i0 + 1, 31);
    float w = sf - (float)i0;
#pragma unroll
    for (int c = 0; c < 5; ++c)
        fbins[c * NBINS + k] = filter_shape_val(c, i0) * (1.f - w) + filter_shape_val(c, i1) * w;
}

extern "C" void kernel_launch(void* const* d_in, const int* in_sizes, int n_in,
                              void* d_out, int out_size, void* d_ws, size_t ws_size,
                              hipStream_t stream)
{
    const float* cond = (const float*)d_in[0];
    const float* f0   = (const float*)d_in[1];
    const float* wn   = (const float*)d_in[2];
    const float* w1   = (const float*)d_in[3];
    const float* b1   = (const float*)d_in[4];
    const float* w2   = (const float*)d_in[5];
    const float* b2   = (const float*)d_in[6];
    const float* w3   = (const float*)d_in[7];
    const float* b3   = (const float*)d_in[8];
    const float* w4   = (const float*)d_in[9];
    const float* b4   = (const float*)d_in[10];

    float* out = (float*)d_out;
    float* filtered = out;
    float* bf_out   = out + (size_t)BB * NA;

    char* ws = (char*)d_ws;
    size_t off = 0;
    float2* I = (float2*)(ws + off);            off += 24576000;
    unsigned short* xpT1 = (unsigned short*)(ws + off); off += (size_t)BB * 212 * 160 * 2;
    unsigned short* xpT2 = (unsigned short*)(ws + off); off += (size_t)BB * 210 * 256 * 2;
    unsigned short* xpT3 = (unsigned short*)(ws + off); off += (size_t)BB * 210 * 128 * 2;
    unsigned short* xpT4 = (unsigned short*)(ws + off); off += (size_t)BB * 200 * 64 * 2;
    unsigned short* wT1  = (unsigned short*)(ws + off); off += (size_t)5 * 256 * 160 * 2;
    unsigned short* wT2  = (unsigned short*)(ws + off); off += (size_t)3 * 128 * 256 * 2;
    unsigned short* wT3  = (unsigned short*)(ws + off); off += (size_t)3 * 64 * 128 * 2;
    float* control   = (float*)(ws + off);
    float* avg_shape = control + 102400;
    float* loc_w     = avg_shape + 2048;
    float* acc       = loc_w + 320;
    float* z0        = acc + 64;
    float* scale     = z0 + 64;
    float* fbins     = scale + 64;

    dim3 blk(256);

    init_kernel<<<1, 64, 0, stream>>>(acc, z0);

    // prep
    {
        int n1 = BB * 212 * 160;
        prep_x1_kernel<<<dim3((n1 + 255) / 256), blk, 0, stream>>>(cond, f0, xpT1);
        int z2 = (BB * 210 * 256 * 2) / 16;
        zero16_kernel<<<dim3((z2 + 255) / 256), blk, 0, stream>>>((uint4*)xpT2, z2);
        int z3 = (BB * 210 * 128 * 2) / 16;
        zero16_kernel<<<dim3((z3 + 255) / 256), blk, 0, stream>>>((uint4*)xpT3, z3);
        prep_w_kernel<5, 129, 160, 256><<<dim3((5 * 256 * 160 + 255) / 256), blk, 0, stream>>>(w1, wT1);
        prep_w_kernel<3, 256, 256, 128><<<dim3((3 * 128 * 256 + 255) / 256), blk, 0, stream>>>(w2, wT2);
        prep_w_kernel<3, 128, 128, 64><<<dim3((3 * 64 * 128 + 255) / 256), blk, 0, stream>>>(w3, wT3);
    }

    // MFMA conv stack
    conv_mfma_kernel<4, 5, 5, 160, 256><<<dim3(13, BB), blk, 0, stream>>>(
        xpT1, 212, wT1, b1, xpT2, 210, 1);
    conv_mfma_kernel<2, 3, 8, 256, 128><<<dim3(13, BB), blk, 0, stream>>>(
        xpT2, 210, wT2, b2, xpT3, 210, 1);
    conv_mfma_kernel<1, 3, 4, 128, 64><<<dim3(13, BB), blk, 0, stream>>>(
        xpT3, 210, wT3, b3, xpT4, 200, 0);

    head_kernel<<<dim3(BB), blk, 0, stream>>>(xpT4, w4, b4, control, avg_shape, bf_out);
    locw_mean_kernel<<<dim3(5, BB), blk, 0, stream>>>(control, loc_w);
    fbins_kernel<<<dim3((NBINS + 255) / 256), blk, 0, stream>>>(fbins);

    // batch-paired four-step FFT pipeline (32 complex signals carry 64 real batches)
    passA_kernel<<<dim3(25, 32), blk, 0, stream>>>(wn, I);
    passBp_kernel<0><<<dim3(20, 32), blk, 0, stream>>>(I, avg_shape, fbins, loc_w, acc, z0);
    finalize_scale<<<1, 64, 0, stream>>>(acc, z0, scale);
    passC_kernel<<<dim3(25, 32), blk, 0, stream>>>(I, control, f0, scale);
    passBp_kernel<1><<<dim3(20, 32), blk, 0, stream>>>(I, avg_shape, fbins, loc_w, acc, z0);
    passD_kernel<<<dim3(25, 32), blk, 0, stream>>>(I, filtered);
}